// Round 1
// baseline (742.759 us; speedup 1.0000x reference)
//
#include <hip/hip_runtime.h>
#include <hip/hip_bf16.h>

#define NN 50000
#define NE 800000

// ---------------- CSR build ----------------

__global__ __launch_bounds__(256) void hist_kernel(const int* __restrict__ dst,
                                                   int* __restrict__ counts) {
  int e = blockIdx.x * 256 + threadIdx.x;
  if (e < NE) atomicAdd(&counts[dst[e]], 1);
}

__global__ __launch_bounds__(1024) void scan1_kernel(const int* __restrict__ counts,
                                                     int* __restrict__ partial,
                                                     int* __restrict__ blockSums) {
  __shared__ int sm[1024];
  int i = blockIdx.x * 1024 + threadIdx.x;
  sm[threadIdx.x] = (i < NN) ? counts[i] : 0;
  __syncthreads();
  for (int off = 1; off < 1024; off <<= 1) {
    int t = (threadIdx.x >= off) ? sm[threadIdx.x - off] : 0;
    __syncthreads();
    sm[threadIdx.x] += t;
    __syncthreads();
  }
  if (i < NN) partial[i] = sm[threadIdx.x];
  if (threadIdx.x == 1023) blockSums[blockIdx.x] = sm[1023];
}

__global__ void scan2_kernel(int* blockSums, int nb) {
  if (threadIdx.x == 0) {
    int run = 0;
    for (int b = 0; b < nb; ++b) { int v = blockSums[b]; blockSums[b] = run; run += v; }
  }
}

__global__ __launch_bounds__(256) void scan3_kernel(const int* __restrict__ partial,
                                                    const int* __restrict__ blockOffs,
                                                    int* __restrict__ rowPtr) {
  int i = blockIdx.x * 256 + threadIdx.x;
  if (i < NN) {
    rowPtr[i + 1] = partial[i] + blockOffs[i >> 10];
    if (i == 0) rowPtr[0] = 0;
  }
}

__global__ __launch_bounds__(256) void fill_kernel(const int* __restrict__ srcArr,
                                                   const int* __restrict__ dstArr,
                                                   const int* __restrict__ rowPtr,
                                                   int* __restrict__ cursor,
                                                   int* __restrict__ colSrc) {
  int e = blockIdx.x * 256 + threadIdx.x;
  if (e < NE) {
    int d = dstArr[e];
    int p = rowPtr[d] + atomicAdd(&cursor[d], 1);
    colSrc[p] = srcArr[e];
  }
}

// ---------------- fp32 tiled GEMM: C[NN,M] = A[NN,K] * B[K,M] ----------------

__global__ __launch_bounds__(256) void gemm64_kernel(const float* __restrict__ A,
                                                     const float* __restrict__ B,
                                                     float* __restrict__ C,
                                                     int K, int M) {
  __shared__ float As[16][68];  // [k][row], +4 pad keeps 16B alignment
  __shared__ float Bs[16][68];  // [k][col]
  const int tid = threadIdx.x;
  const int tx = tid & 15, ty = tid >> 4;
  const int rowBase = blockIdx.y * 64;
  const int colBase = blockIdx.x * 64;
  const int lr = tid >> 2;           // A-load row 0..63
  const int lk = (tid & 3) * 4;      // A-load k offset
  const int bk = tid >> 4;           // B-load k 0..15
  const int bc = (tid & 15) * 4;     // B-load col
  float acc[4][4] = {};
  for (int k0 = 0; k0 < K; k0 += 16) {
    int gr = rowBase + lr;
    float4 a = make_float4(0.f, 0.f, 0.f, 0.f);
    if (gr < NN) a = *(const float4*)(A + (size_t)gr * K + k0 + lk);
    As[lk + 0][lr] = a.x; As[lk + 1][lr] = a.y; As[lk + 2][lr] = a.z; As[lk + 3][lr] = a.w;
    int gc = colBase + bc;
    float4 b;
    if (gc + 3 < M) {
      b = *(const float4*)(B + (size_t)(k0 + bk) * M + gc);
    } else {
      b.x = (gc + 0 < M) ? B[(size_t)(k0 + bk) * M + gc + 0] : 0.f;
      b.y = (gc + 1 < M) ? B[(size_t)(k0 + bk) * M + gc + 1] : 0.f;
      b.z = (gc + 2 < M) ? B[(size_t)(k0 + bk) * M + gc + 2] : 0.f;
      b.w = (gc + 3 < M) ? B[(size_t)(k0 + bk) * M + gc + 3] : 0.f;
    }
    *(float4*)&Bs[bk][bc] = b;
    __syncthreads();
#pragma unroll
    for (int k = 0; k < 16; ++k) {
      float4 av = *(const float4*)&As[k][ty * 4];
      float4 bv = *(const float4*)&Bs[k][tx * 4];
      float aa[4] = {av.x, av.y, av.z, av.w};
      float bb[4] = {bv.x, bv.y, bv.z, bv.w};
#pragma unroll
      for (int i = 0; i < 4; ++i)
#pragma unroll
        for (int j = 0; j < 4; ++j) acc[i][j] += aa[i] * bb[j];
    }
    __syncthreads();
  }
#pragma unroll
  for (int i = 0; i < 4; ++i) {
    int r = rowBase + ty * 4 + i;
    if (r >= NN) break;
    int c = colBase + tx * 4;
    if (c + 3 < M) {
      *(float4*)(C + (size_t)r * M + c) = make_float4(acc[i][0], acc[i][1], acc[i][2], acc[i][3]);
    } else {
#pragma unroll
      for (int j = 0; j < 4; ++j)
        if (c + j < M) C[(size_t)r * M + c + j] = acc[i][j];
    }
  }
}

// ---------------- per-node attention logits ----------------

__global__ __launch_bounds__(256) void logits256_kernel(const float* __restrict__ xw,
                                                        const float* __restrict__ attS,
                                                        const float* __restrict__ attD,
                                                        float* __restrict__ asOut,
                                                        float* __restrict__ adOut) {
  const int n = (blockIdx.x * blockDim.x + threadIdx.x) >> 6;
  if (n >= NN) return;
  const int lane = threadIdx.x & 63;
  const float4 x = *(const float4*)(xw + (size_t)n * 256 + lane * 4);
  const float4 s4 = *(const float4*)(attS + lane * 4);
  const float4 d4 = *(const float4*)(attD + lane * 4);
  float ps = x.x * s4.x + x.y * s4.y + x.z * s4.z + x.w * s4.w;
  float pd = x.x * d4.x + x.y * d4.y + x.z * d4.z + x.w * d4.w;
#pragma unroll
  for (int o = 1; o < 16; o <<= 1) { ps += __shfl_xor(ps, o); pd += __shfl_xor(pd, o); }
  if ((lane & 15) == 0) {
    asOut[n * 4 + (lane >> 4)] = ps;
    adOut[n * 4 + (lane >> 4)] = pd;
  }
}

__global__ __launch_bounds__(256) void logits40_kernel(const float* __restrict__ xw,
                                                       const float* __restrict__ attS,
                                                       const float* __restrict__ attD,
                                                       float* __restrict__ asOut,
                                                       float* __restrict__ adOut) {
  const int n = (blockIdx.x * blockDim.x + threadIdx.x) >> 6;
  if (n >= NN) return;
  const int lane = threadIdx.x & 63;
  const bool act = lane < 40;
  float x = act ? xw[(size_t)n * 40 + lane] : 0.f;
  float sv = act ? attS[lane] : 0.f;
  float dv = act ? attD[lane] : 0.f;
  float ps = x * sv, pd = x * dv;
#pragma unroll
  for (int o = 1; o < 64; o <<= 1) { ps += __shfl_xor(ps, o); pd += __shfl_xor(pd, o); }
  if (lane == 0) { asOut[n] = ps; adOut[n] = pd; }
}

// ---------------- aggregation: wave per dst node, online softmax ----------------

__global__ __launch_bounds__(256) void aggregate256_kernel(
    const float* __restrict__ xw, const float* __restrict__ asB, const float* __restrict__ adB,
    const int* __restrict__ rowPtr, const int* __restrict__ colSrc,
    const float* __restrict__ bias, float* __restrict__ hout, int applyElu) {
  const int n = (blockIdx.x * blockDim.x + threadIdx.x) >> 6;
  if (n >= NN) return;
  const int lane = threadIdx.x & 63;
  const int h = lane >> 4;
  const int ch = lane * 4;
  const float adn = adB[n * 4 + h];
  // self loop (always present) is the init element
  float e = asB[n * 4 + h] + adn;
  e = e > 0.f ? e : 0.2f * e;
  float m = e, s = 1.f;
  float4 acc = *(const float4*)(xw + (size_t)n * 256 + ch);
  const int end = rowPtr[n + 1];
  for (int p = rowPtr[n]; p < end; ++p) {
    const int src = colSrc[p];
    float ev = asB[src * 4 + h] + adn;
    ev = ev > 0.f ? ev : 0.2f * ev;
    const float4 xv = *(const float4*)(xw + (size_t)src * 256 + ch);
    if (ev <= m) {
      const float w = __expf(ev - m);
      s += w;
      acc.x += w * xv.x; acc.y += w * xv.y; acc.z += w * xv.z; acc.w += w * xv.w;
    } else {
      const float sc = __expf(m - ev);
      s = s * sc + 1.f;
      acc.x = acc.x * sc + xv.x; acc.y = acc.y * sc + xv.y;
      acc.z = acc.z * sc + xv.z; acc.w = acc.w * sc + xv.w;
      m = ev;
    }
  }
  const float inv = 1.f / (s + 1e-16f);
  const float4 b4 = *(const float4*)(bias + ch);
  float o0 = acc.x * inv + b4.x, o1 = acc.y * inv + b4.y;
  float o2 = acc.z * inv + b4.z, o3 = acc.w * inv + b4.w;
  if (applyElu) {
    o0 = o0 > 0.f ? o0 : __expf(o0) - 1.f;
    o1 = o1 > 0.f ? o1 : __expf(o1) - 1.f;
    o2 = o2 > 0.f ? o2 : __expf(o2) - 1.f;
    o3 = o3 > 0.f ? o3 : __expf(o3) - 1.f;
  }
  *(float4*)(hout + (size_t)n * 256 + ch) = make_float4(o0, o1, o2, o3);
}

__global__ __launch_bounds__(256) void aggregate40_lsm_kernel(
    const float* __restrict__ xw, const float* __restrict__ asB, const float* __restrict__ adB,
    const int* __restrict__ rowPtr, const int* __restrict__ colSrc,
    const float* __restrict__ bias, float* __restrict__ out) {
  const int n = (blockIdx.x * blockDim.x + threadIdx.x) >> 6;
  if (n >= NN) return;
  const int lane = threadIdx.x & 63;
  const bool act = lane < 40;
  const float adn = adB[n];
  float e = asB[n] + adn;
  e = e > 0.f ? e : 0.2f * e;
  float m = e, s = 1.f;
  float acc = act ? xw[(size_t)n * 40 + lane] : 0.f;
  const int end = rowPtr[n + 1];
  for (int p = rowPtr[n]; p < end; ++p) {
    const int src = colSrc[p];
    float ev = asB[src] + adn;
    ev = ev > 0.f ? ev : 0.2f * ev;
    const float xv = act ? xw[(size_t)src * 40 + lane] : 0.f;
    if (ev <= m) {
      const float w = __expf(ev - m);
      s += w; acc += w * xv;
    } else {
      const float sc = __expf(m - ev);
      s = s * sc + 1.f; acc = acc * sc + xv; m = ev;
    }
  }
  float val = acc / (s + 1e-16f) + (act ? bias[lane] : 0.f);
  // fused log_softmax over the 40 classes (held in lanes 0..39)
  float v = act ? val : -1e30f;
  float mx = v;
#pragma unroll
  for (int o = 1; o < 64; o <<= 1) mx = fmaxf(mx, __shfl_xor(mx, o));
  float ex = act ? __expf(val - mx) : 0.f;
#pragma unroll
  for (int o = 1; o < 64; o <<= 1) ex += __shfl_xor(ex, o);
  if (act) out[(size_t)n * 40 + lane] = val - mx - __logf(ex);
}

// ---------------- launch ----------------

extern "C" void kernel_launch(void* const* d_in, const int* in_sizes, int n_in,
                              void* d_out, int out_size, void* d_ws, size_t ws_size,
                              hipStream_t stream) {
  const float* x   = (const float*)d_in[0];
  const int*   ei  = (const int*)d_in[1];   // [2, NE]: row 0 src, row 1 dst
  const float* W1  = (const float*)d_in[2];
  const float* a1s = (const float*)d_in[3];
  const float* a1d = (const float*)d_in[4];
  const float* b1  = (const float*)d_in[5];
  const float* W2  = (const float*)d_in[6];
  const float* a2s = (const float*)d_in[7];
  const float* a2d = (const float*)d_in[8];
  const float* b2  = (const float*)d_in[9];
  const float* W3  = (const float*)d_in[10];
  const float* a3s = (const float*)d_in[11];
  const float* a3d = (const float*)d_in[12];
  const float* b3  = (const float*)d_in[13];
  float* out = (float*)d_out;

  char* w = (char*)d_ws;
  float* xwBuf = (float*)w;  w += (size_t)NN * 256 * 4;
  float* hBuf  = (float*)w;  w += (size_t)NN * 256 * 4;
  float* asBuf = (float*)w;  w += (size_t)NN * 4 * 4;
  float* adBuf = (float*)w;  w += (size_t)NN * 4 * 4;
  int* counts  = (int*)w;    w += (size_t)NN * 4;
  int* cursor  = (int*)w;    w += (size_t)NN * 4;
  int* rowPtr  = (int*)w;    w += (size_t)(NN + 1) * 4;
  int* colSrc  = (int*)w;    w += (size_t)NE * 4;
  int* partial = (int*)w;    w += (size_t)NN * 4;
  int* blockSums = (int*)w;  w += 64 * 4;

  const int nScanBlocks = (NN + 1023) / 1024;  // 49

  // CSR build (counts & cursor are adjacent -> one memset)
  hipMemsetAsync(counts, 0, (size_t)2 * NN * 4, stream);
  hist_kernel<<<(NE + 255) / 256, 256, 0, stream>>>(ei + NE, counts);
  scan1_kernel<<<nScanBlocks, 1024, 0, stream>>>(counts, partial, blockSums);
  scan2_kernel<<<1, 64, 0, stream>>>(blockSums, nScanBlocks);
  scan3_kernel<<<(NN + 255) / 256, 256, 0, stream>>>(partial, blockSums, rowPtr);
  fill_kernel<<<(NE + 255) / 256, 256, 0, stream>>>(ei, ei + NE, rowPtr, cursor, colSrc);

  const int nodeBlocks = NN / 4;  // wave per node, 4 waves/block = 12500

  // layer 1: 128 -> 4x64
  gemm64_kernel<<<dim3(4, (NN + 63) / 64), 256, 0, stream>>>(x, W1, xwBuf, 128, 256);
  logits256_kernel<<<nodeBlocks, 256, 0, stream>>>(xwBuf, a1s, a1d, asBuf, adBuf);
  aggregate256_kernel<<<nodeBlocks, 256, 0, stream>>>(xwBuf, asBuf, adBuf, rowPtr, colSrc, b1, hBuf, 1);

  // layer 2: 256 -> 4x64
  gemm64_kernel<<<dim3(4, (NN + 63) / 64), 256, 0, stream>>>(hBuf, W2, xwBuf, 256, 256);
  logits256_kernel<<<nodeBlocks, 256, 0, stream>>>(xwBuf, a2s, a2d, asBuf, adBuf);
  aggregate256_kernel<<<nodeBlocks, 256, 0, stream>>>(xwBuf, asBuf, adBuf, rowPtr, colSrc, b2, hBuf, 1);

  // layer 3: 256 -> 40, then log_softmax
  gemm64_kernel<<<dim3(1, (NN + 63) / 64), 256, 0, stream>>>(hBuf, W3, xwBuf, 256, 40);
  logits40_kernel<<<nodeBlocks, 256, 0, stream>>>(xwBuf, a3s, a3d, asBuf, adBuf);
  aggregate40_lsm_kernel<<<nodeBlocks, 256, 0, stream>>>(xwBuf, asBuf, adBuf, rowPtr, colSrc, b3, out);
}

// Round 2
// 640.961 us; speedup vs baseline: 1.1588x; 1.1588x over previous
//
#include <hip/hip_runtime.h>
#include <hip/hip_bf16.h>

#define NN 50000
#define NE 800000

using bf16x8 = __attribute__((ext_vector_type(8))) short;
using f32x4  = __attribute__((ext_vector_type(4))) float;

__device__ __forceinline__ ushort f2bf(float f) {
  uint x = __float_as_uint(f);
  return (ushort)((x + 0x7FFFu + ((x >> 16) & 1u)) >> 16);
}
__device__ __forceinline__ float bf2f(ushort u) {
  return __uint_as_float(((uint)u) << 16);
}

// ---------------- CSR build ----------------

__global__ __launch_bounds__(256) void hist_kernel(const int* __restrict__ dst,
                                                   int* __restrict__ counts) {
  int e = blockIdx.x * 256 + threadIdx.x;
  if (e < NE) atomicAdd(&counts[dst[e]], 1);
}

__global__ __launch_bounds__(1024) void scan1_kernel(const int* __restrict__ counts,
                                                     int* __restrict__ partial,
                                                     int* __restrict__ blockSums) {
  __shared__ int sm[1024];
  int i = blockIdx.x * 1024 + threadIdx.x;
  sm[threadIdx.x] = (i < NN) ? counts[i] : 0;
  __syncthreads();
  for (int off = 1; off < 1024; off <<= 1) {
    int t = (threadIdx.x >= off) ? sm[threadIdx.x - off] : 0;
    __syncthreads();
    sm[threadIdx.x] += t;
    __syncthreads();
  }
  if (i < NN) partial[i] = sm[threadIdx.x];
  if (threadIdx.x == 1023) blockSums[blockIdx.x] = sm[1023];
}

__global__ void scan2_kernel(int* blockSums, int nb) {
  if (threadIdx.x == 0) {
    int run = 0;
    for (int b = 0; b < nb; ++b) { int v = blockSums[b]; blockSums[b] = run; run += v; }
  }
}

__global__ __launch_bounds__(256) void scan3_kernel(const int* __restrict__ partial,
                                                    const int* __restrict__ blockOffs,
                                                    int* __restrict__ rowPtr) {
  int i = blockIdx.x * 256 + threadIdx.x;
  if (i < NN) {
    rowPtr[i + 1] = partial[i] + blockOffs[i >> 10];
    if (i == 0) rowPtr[0] = 0;
  }
}

__global__ __launch_bounds__(256) void fill_kernel(const int* __restrict__ srcArr,
                                                   const int* __restrict__ dstArr,
                                                   const int* __restrict__ rowPtr,
                                                   int* __restrict__ cursor,
                                                   int* __restrict__ colSrc) {
  int e = blockIdx.x * 256 + threadIdx.x;
  if (e < NE) {
    int d = dstArr[e];
    int p = rowPtr[d] + atomicAdd(&cursor[d], 1);
    colSrc[p] = srcArr[e];
  }
}

// ---------------- fp32 -> bf16 convert (input features) ----------------

__global__ __launch_bounds__(256) void f2bf_kernel(const float* __restrict__ in,
                                                   ushort* __restrict__ out, int n4) {
  int i = blockIdx.x * 256 + threadIdx.x;
  if (i < n4) {
    float4 v = *(const float4*)(in + (size_t)i * 4);
    ushort4 o;
    o.x = f2bf(v.x); o.y = f2bf(v.y); o.z = f2bf(v.z); o.w = f2bf(v.w);
    *(ushort4*)(out + (size_t)i * 4) = o;
  }
}

// ---------------- pre-fragment B' = [W | W@att_s | W@att_d | 0] into MFMA lane order ----------------
// Bf[((ct*KC + kc)*64 + lane)*8 + i] = B'[kc*32 + (lane>>4)*8 + i][ct*16 + (lane&15)]

__global__ __launch_bounds__(256) void prefrag_kernel(const float* __restrict__ W,
                                                      const float* __restrict__ atS,
                                                      const float* __restrict__ atD,
                                                      ushort* __restrict__ Bf,
                                                      int K, int Mout, int nh, int Cdim, int NCT) {
  int idx = blockIdx.x * 256 + threadIdx.x;
  const int KC = K >> 5;
  const int total = NCT * KC * 512;
  if (idx >= total) return;
  int i = idx & 7;
  int lane = (idx >> 3) & 63;
  int kc = (idx >> 9) % KC;
  int ct = idx / (KC * 512);
  int k = kc * 32 + (lane >> 4) * 8 + i;
  int col = ct * 16 + (lane & 15);
  float v = 0.f;
  if (col < Mout) {
    v = W[(size_t)k * Mout + col];
  } else if (col < Mout + nh) {
    int h = col - Mout; float s = 0.f;
    for (int c = 0; c < Cdim; ++c) s += W[(size_t)k * Mout + h * Cdim + c] * atS[h * Cdim + c];
    v = s;
  } else if (col < Mout + 2 * nh) {
    int h = col - Mout - nh; float s = 0.f;
    for (int c = 0; c < Cdim; ++c) s += W[(size_t)k * Mout + h * Cdim + c] * atD[h * Cdim + c];
    v = s;
  }
  Bf[idx] = f2bf(v);
}

// ---------------- LDS-free bf16 MFMA GEMM with fused logit columns ----------------
// A [NN x K] bf16 row-major. Bf pre-fragmented. Writes xw bf16 [NN x Mout],
// asB/adB fp32 [NN x nh] from the appended columns.

template <int NCT>
__global__ __launch_bounds__(256) void gemm_mfma_kernel(const ushort* __restrict__ A,
                                                        const ushort* __restrict__ Bf,
                                                        ushort* __restrict__ xw,
                                                        float* __restrict__ asB,
                                                        float* __restrict__ adB,
                                                        int K, int Mout, int nh) {
  const int lane = threadIdx.x & 63;
  const int w = threadIdx.x >> 6;
  const int rowBase = blockIdx.x * 64 + w * 16;
  if (rowBase >= NN) return;
  const int KC = K >> 5;
  const int arow = rowBase + (lane & 15);          // A frag: row = lane&15
  const int koff = (lane >> 4) * 8;                // k = (lane>>4)*8 + i
  f32x4 acc[NCT];
#pragma unroll
  for (int ct = 0; ct < NCT; ++ct) acc[ct] = (f32x4){0.f, 0.f, 0.f, 0.f};
  const ushort* aptr = A + (size_t)arow * K + koff;
  for (int kc = 0; kc < KC; ++kc) {
    bf16x8 af = *reinterpret_cast<const bf16x8*>(aptr + kc * 32);
    const ushort* bp = Bf + (size_t)kc * 512 + lane * 8;
#pragma unroll
    for (int ct = 0; ct < NCT; ++ct) {
      bf16x8 bfr = *reinterpret_cast<const bf16x8*>(bp + (size_t)ct * KC * 512);
      acc[ct] = __builtin_amdgcn_mfma_f32_16x16x32_bf16(af, bfr, acc[ct], 0, 0, 0);
    }
  }
  // epilogue: D mapping col = lane&15, row = (lane>>4)*4 + reg
  const int colL = lane & 15;
  const int rquad = (lane >> 4) * 4;
#pragma unroll
  for (int ct = 0; ct < NCT; ++ct) {
    const int col = ct * 16 + colL;
#pragma unroll
    for (int r = 0; r < 4; ++r) {
      const int row = rowBase + rquad + r;
      const float v = acc[ct][r];
      if (col < Mout) {
        xw[(size_t)row * Mout + col] = f2bf(v);
      } else if (col < Mout + nh) {
        asB[(size_t)row * nh + (col - Mout)] = v;
      } else if (col < Mout + 2 * nh) {
        adB[(size_t)row * nh + (col - Mout - nh)] = v;
      }
    }
  }
}

// ---------------- aggregation: wave per dst node, online softmax, bf16 messages ----------------

__global__ __launch_bounds__(256) void aggregate256_kernel(
    const ushort* __restrict__ xw, const float* __restrict__ asB, const float* __restrict__ adB,
    const int* __restrict__ rowPtr, const int* __restrict__ colSrc,
    const float* __restrict__ bias, ushort* __restrict__ hout, int applyElu) {
  const int n = (blockIdx.x * blockDim.x + threadIdx.x) >> 6;
  if (n >= NN) return;
  const int lane = threadIdx.x & 63;
  const int h = lane >> 4;
  const int ch = lane * 4;
  const float adn = adB[n * 4 + h];
  float e = asB[n * 4 + h] + adn;
  e = e > 0.f ? e : 0.2f * e;
  float m = e, s = 1.f;
  ushort4 xv4 = *(const ushort4*)(xw + (size_t)n * 256 + ch);
  float4 acc = make_float4(bf2f(xv4.x), bf2f(xv4.y), bf2f(xv4.z), bf2f(xv4.w));
  const int end = rowPtr[n + 1];
  for (int p = rowPtr[n]; p < end; ++p) {
    const int src = colSrc[p];
    float ev = asB[src * 4 + h] + adn;
    ev = ev > 0.f ? ev : 0.2f * ev;
    const ushort4 u4 = *(const ushort4*)(xw + (size_t)src * 256 + ch);
    const float x0 = bf2f(u4.x), x1 = bf2f(u4.y), x2 = bf2f(u4.z), x3 = bf2f(u4.w);
    if (ev <= m) {
      const float wgt = __expf(ev - m);
      s += wgt;
      acc.x += wgt * x0; acc.y += wgt * x1; acc.z += wgt * x2; acc.w += wgt * x3;
    } else {
      const float sc = __expf(m - ev);
      s = s * sc + 1.f;
      acc.x = acc.x * sc + x0; acc.y = acc.y * sc + x1;
      acc.z = acc.z * sc + x2; acc.w = acc.w * sc + x3;
      m = ev;
    }
  }
  const float inv = 1.f / (s + 1e-16f);
  const float4 b4 = *(const float4*)(bias + ch);
  float o0 = acc.x * inv + b4.x, o1 = acc.y * inv + b4.y;
  float o2 = acc.z * inv + b4.z, o3 = acc.w * inv + b4.w;
  if (applyElu) {
    o0 = o0 > 0.f ? o0 : __expf(o0) - 1.f;
    o1 = o1 > 0.f ? o1 : __expf(o1) - 1.f;
    o2 = o2 > 0.f ? o2 : __expf(o2) - 1.f;
    o3 = o3 > 0.f ? o3 : __expf(o3) - 1.f;
  }
  ushort4 o4;
  o4.x = f2bf(o0); o4.y = f2bf(o1); o4.z = f2bf(o2); o4.w = f2bf(o3);
  *(ushort4*)(hout + (size_t)n * 256 + ch) = o4;
}

__global__ __launch_bounds__(256) void aggregate40_lsm_kernel(
    const ushort* __restrict__ xw, const float* __restrict__ asB, const float* __restrict__ adB,
    const int* __restrict__ rowPtr, const int* __restrict__ colSrc,
    const float* __restrict__ bias, float* __restrict__ out) {
  const int n = (blockIdx.x * blockDim.x + threadIdx.x) >> 6;
  if (n >= NN) return;
  const int lane = threadIdx.x & 63;
  const bool act = lane < 40;
  const float adn = adB[n];
  float e = asB[n] + adn;
  e = e > 0.f ? e : 0.2f * e;
  float m = e, s = 1.f;
  float acc = act ? bf2f(xw[(size_t)n * 40 + lane]) : 0.f;
  const int end = rowPtr[n + 1];
  for (int p = rowPtr[n]; p < end; ++p) {
    const int src = colSrc[p];
    float ev = asB[src] + adn;
    ev = ev > 0.f ? ev : 0.2f * ev;
    const float xv = act ? bf2f(xw[(size_t)src * 40 + lane]) : 0.f;
    if (ev <= m) {
      const float wgt = __expf(ev - m);
      s += wgt; acc += wgt * xv;
    } else {
      const float sc = __expf(m - ev);
      s = s * sc + 1.f; acc = acc * sc + xv; m = ev;
    }
  }
  float val = acc / (s + 1e-16f) + (act ? bias[lane] : 0.f);
  float v = act ? val : -1e30f;
  float mx = v;
#pragma unroll
  for (int o = 1; o < 64; o <<= 1) mx = fmaxf(mx, __shfl_xor(mx, o));
  float ex = act ? __expf(val - mx) : 0.f;
#pragma unroll
  for (int o = 1; o < 64; o <<= 1) ex += __shfl_xor(ex, o);
  if (act) out[(size_t)n * 40 + lane] = val - mx - __logf(ex);
}

// ---------------- launch ----------------

extern "C" void kernel_launch(void* const* d_in, const int* in_sizes, int n_in,
                              void* d_out, int out_size, void* d_ws, size_t ws_size,
                              hipStream_t stream) {
  const float* x   = (const float*)d_in[0];
  const int*   ei  = (const int*)d_in[1];
  const float* W1  = (const float*)d_in[2];
  const float* a1s = (const float*)d_in[3];
  const float* a1d = (const float*)d_in[4];
  const float* b1  = (const float*)d_in[5];
  const float* W2  = (const float*)d_in[6];
  const float* a2s = (const float*)d_in[7];
  const float* a2d = (const float*)d_in[8];
  const float* b2  = (const float*)d_in[9];
  const float* W3  = (const float*)d_in[10];
  const float* a3s = (const float*)d_in[11];
  const float* a3d = (const float*)d_in[12];
  const float* b3  = (const float*)d_in[13];
  float* out = (float*)d_out;

  char* w = (char*)d_ws;
  ushort* xbBuf = (ushort*)w;  w += (size_t)NN * 128 * 2;   // x in bf16
  ushort* xwBuf = (ushort*)w;  w += (size_t)NN * 256 * 2;   // per-layer xw (bf16)
  ushort* hBuf  = (ushort*)w;  w += (size_t)NN * 256 * 2;   // layer outputs (bf16)
  ushort* xw40  = (ushort*)w;  w += (size_t)NN * 40 * 2;
  float* asBuf  = (float*)w;   w += (size_t)NN * 4 * 4;
  float* adBuf  = (float*)w;   w += (size_t)NN * 4 * 4;
  ushort* Bf1   = (ushort*)w;  w += (size_t)17 * 4 * 512 * 2;   // NCT=17, KC=4
  ushort* Bf2   = (ushort*)w;  w += (size_t)17 * 8 * 512 * 2;   // NCT=17, KC=8
  ushort* Bf3   = (ushort*)w;  w += (size_t)3 * 8 * 512 * 2;    // NCT=3,  KC=8
  int* counts   = (int*)w;     w += (size_t)NN * 4;
  int* cursor   = (int*)w;     w += (size_t)NN * 4;
  int* rowPtr   = (int*)w;     w += (size_t)(NN + 1) * 4;
  int* colSrc   = (int*)w;     w += (size_t)NE * 4;
  int* partial  = (int*)w;     w += (size_t)NN * 4;
  int* blockSums = (int*)w;    w += 64 * 4;

  const int nScanBlocks = (NN + 1023) / 1024;

  // CSR build
  hipMemsetAsync(counts, 0, (size_t)2 * NN * 4, stream);
  hist_kernel<<<(NE + 255) / 256, 256, 0, stream>>>(ei + NE, counts);
  scan1_kernel<<<nScanBlocks, 1024, 0, stream>>>(counts, partial, blockSums);
  scan2_kernel<<<1, 64, 0, stream>>>(blockSums, nScanBlocks);
  scan3_kernel<<<(NN + 255) / 256, 256, 0, stream>>>(partial, blockSums, rowPtr);
  fill_kernel<<<(NE + 255) / 256, 256, 0, stream>>>(ei, ei + NE, rowPtr, cursor, colSrc);

  // x -> bf16
  f2bf_kernel<<<(NN * 128 / 4 + 255) / 256, 256, 0, stream>>>(x, xbBuf, NN * 128 / 4);

  // pre-fragment weights (+ fused logit columns)
  prefrag_kernel<<<(17 * 4 * 512 + 255) / 256, 256, 0, stream>>>(W1, a1s, a1d, Bf1, 128, 256, 4, 64, 17);
  prefrag_kernel<<<(17 * 8 * 512 + 255) / 256, 256, 0, stream>>>(W2, a2s, a2d, Bf2, 256, 256, 4, 64, 17);
  prefrag_kernel<<<(3 * 8 * 512 + 255) / 256, 256, 0, stream>>>(W3, a3s, a3d, Bf3, 256, 40, 1, 40, 3);

  const int gemmBlocks = (NN + 63) / 64;  // 782
  const int nodeBlocks = NN / 4;          // wave per node

  // layer 1: 128 -> 4x64
  gemm_mfma_kernel<17><<<gemmBlocks, 256, 0, stream>>>(xbBuf, Bf1, xwBuf, asBuf, adBuf, 128, 256, 4);
  aggregate256_kernel<<<nodeBlocks, 256, 0, stream>>>(xwBuf, asBuf, adBuf, rowPtr, colSrc, b1, hBuf, 1);

  // layer 2: 256 -> 4x64
  gemm_mfma_kernel<17><<<gemmBlocks, 256, 0, stream>>>(hBuf, Bf2, xwBuf, asBuf, adBuf, 256, 256, 4);
  aggregate256_kernel<<<nodeBlocks, 256, 0, stream>>>(xwBuf, asBuf, adBuf, rowPtr, colSrc, b2, hBuf, 1);

  // layer 3: 256 -> 40 (+ log_softmax)
  gemm_mfma_kernel<3><<<gemmBlocks, 256, 0, stream>>>(hBuf, Bf3, xw40, asBuf, adBuf, 256, 40, 1);
  aggregate40_lsm_kernel<<<nodeBlocks, 256, 0, stream>>>(xw40, asBuf, adBuf, rowPtr, colSrc, b3, out);
}

// Round 3
// 574.117 us; speedup vs baseline: 1.2937x; 1.1164x over previous
//
#include <hip/hip_runtime.h>
#include <hip/hip_bf16.h>

#define NN 50000
#define NE 800000

using bf16x8 = __attribute__((ext_vector_type(8))) short;
using f32x4  = __attribute__((ext_vector_type(4))) float;

__device__ __forceinline__ ushort f2bf(float f) {
  uint x = __float_as_uint(f);
  return (ushort)((x + 0x7FFFu + ((x >> 16) & 1u)) >> 16);
}
__device__ __forceinline__ float bf2f(ushort u) {
  return __uint_as_float(((uint)u) << 16);
}
__device__ __forceinline__ float leaky(float x) { return fmaxf(x, 0.2f * x); }

// ---------------- CSR build ----------------

__global__ __launch_bounds__(256) void hist_kernel(const int* __restrict__ dst,
                                                   int* __restrict__ counts) {
  int e = blockIdx.x * 256 + threadIdx.x;
  if (e < NE) atomicAdd(&counts[dst[e]], 1);
}

__global__ __launch_bounds__(1024) void scan1_kernel(const int* __restrict__ counts,
                                                     int* __restrict__ partial,
                                                     int* __restrict__ blockSums) {
  __shared__ int sm[1024];
  int i = blockIdx.x * 1024 + threadIdx.x;
  sm[threadIdx.x] = (i < NN) ? counts[i] : 0;
  __syncthreads();
  for (int off = 1; off < 1024; off <<= 1) {
    int t = (threadIdx.x >= off) ? sm[threadIdx.x - off] : 0;
    __syncthreads();
    sm[threadIdx.x] += t;
    __syncthreads();
  }
  if (i < NN) partial[i] = sm[threadIdx.x];
  if (threadIdx.x == 1023) blockSums[blockIdx.x] = sm[1023];
}

__global__ void scan2_kernel(int* blockSums, int nb) {
  if (threadIdx.x == 0) {
    int run = 0;
    for (int b = 0; b < nb; ++b) { int v = blockSums[b]; blockSums[b] = run; run += v; }
  }
}

__global__ __launch_bounds__(256) void scan3_kernel(const int* __restrict__ partial,
                                                    const int* __restrict__ blockOffs,
                                                    int* __restrict__ rowPtr) {
  int i = blockIdx.x * 256 + threadIdx.x;
  if (i < NN) {
    rowPtr[i + 1] = partial[i] + blockOffs[i >> 10];
    if (i == 0) rowPtr[0] = 0;
  }
}

__global__ __launch_bounds__(256) void fill_kernel(const int* __restrict__ srcArr,
                                                   const int* __restrict__ dstArr,
                                                   const int* __restrict__ rowPtr,
                                                   int* __restrict__ cursor,
                                                   int* __restrict__ colSrc) {
  int e = blockIdx.x * 256 + threadIdx.x;
  if (e < NE) {
    int d = dstArr[e];
    int p = rowPtr[d] + atomicAdd(&cursor[d], 1);
    colSrc[p] = srcArr[e];
  }
}

// ---------------- fp32 -> bf16 convert (input features) ----------------

__global__ __launch_bounds__(256) void f2bf_kernel(const float* __restrict__ in,
                                                   ushort* __restrict__ out, int n4) {
  int i = blockIdx.x * 256 + threadIdx.x;
  if (i < n4) {
    float4 v = *(const float4*)(in + (size_t)i * 4);
    ushort4 o;
    o.x = f2bf(v.x); o.y = f2bf(v.y); o.z = f2bf(v.z); o.w = f2bf(v.w);
    *(ushort4*)(out + (size_t)i * 4) = o;
  }
}

// ---------------- pre-fragment B' = [W | W@att_s | W@att_d | 0] into MFMA lane order ----------------

__global__ __launch_bounds__(256) void prefrag_kernel(const float* __restrict__ W,
                                                      const float* __restrict__ atS,
                                                      const float* __restrict__ atD,
                                                      ushort* __restrict__ Bf,
                                                      int K, int Mout, int nh, int Cdim, int NCT) {
  int idx = blockIdx.x * 256 + threadIdx.x;
  const int KC = K >> 5;
  const int total = NCT * KC * 512;
  if (idx >= total) return;
  int i = idx & 7;
  int lane = (idx >> 3) & 63;
  int kc = (idx >> 9) % KC;
  int ct = idx / (KC * 512);
  int k = kc * 32 + (lane >> 4) * 8 + i;
  int col = ct * 16 + (lane & 15);
  float v = 0.f;
  if (col < Mout) {
    v = W[(size_t)k * Mout + col];
  } else if (col < Mout + nh) {
    int h = col - Mout; float s = 0.f;
    for (int c = 0; c < Cdim; ++c) s += W[(size_t)k * Mout + h * Cdim + c] * atS[h * Cdim + c];
    v = s;
  } else if (col < Mout + 2 * nh) {
    int h = col - Mout - nh; float s = 0.f;
    for (int c = 0; c < Cdim; ++c) s += W[(size_t)k * Mout + h * Cdim + c] * atD[h * Cdim + c];
    v = s;
  }
  Bf[idx] = f2bf(v);
}

// ---------------- LDS-free bf16 MFMA GEMM with fused logit columns ----------------

template <int NCT>
__global__ __launch_bounds__(256) void gemm_mfma_kernel(const ushort* __restrict__ A,
                                                        const ushort* __restrict__ Bf,
                                                        ushort* __restrict__ xw,
                                                        float* __restrict__ asB,
                                                        float* __restrict__ adB,
                                                        int K, int Mout, int nh) {
  const int lane = threadIdx.x & 63;
  const int w = threadIdx.x >> 6;
  const int rowBase = blockIdx.x * 64 + w * 16;
  if (rowBase >= NN) return;
  const int KC = K >> 5;
  const int arow = rowBase + (lane & 15);
  const int koff = (lane >> 4) * 8;
  f32x4 acc[NCT];
#pragma unroll
  for (int ct = 0; ct < NCT; ++ct) acc[ct] = (f32x4){0.f, 0.f, 0.f, 0.f};
  const ushort* aptr = A + (size_t)arow * K + koff;
  for (int kc = 0; kc < KC; ++kc) {
    bf16x8 af = *reinterpret_cast<const bf16x8*>(aptr + kc * 32);
    const ushort* bp = Bf + (size_t)kc * 512 + lane * 8;
#pragma unroll
    for (int ct = 0; ct < NCT; ++ct) {
      bf16x8 bfr = *reinterpret_cast<const bf16x8*>(bp + (size_t)ct * KC * 512);
      acc[ct] = __builtin_amdgcn_mfma_f32_16x16x32_bf16(af, bfr, acc[ct], 0, 0, 0);
    }
  }
  const int colL = lane & 15;
  const int rquad = (lane >> 4) * 4;
#pragma unroll
  for (int ct = 0; ct < NCT; ++ct) {
    const int col = ct * 16 + colL;
#pragma unroll
    for (int r = 0; r < 4; ++r) {
      const int row = rowBase + rquad + r;
      const float v = acc[ct][r];
      if (col < Mout) {
        xw[(size_t)row * Mout + col] = f2bf(v);
      } else if (col < Mout + nh) {
        asB[(size_t)row * nh + (col - Mout)] = v;
      } else if (col < Mout + 2 * nh) {
        adB[(size_t)row * nh + (col - Mout - nh)] = v;
      }
    }
  }
}

// ---------------- aggregation: wave/node, 2-pass (max, then weight+gather), unroll-4 MLP ----------------

__global__ __launch_bounds__(256) void aggregate256_kernel(
    const ushort* __restrict__ xw, const float* __restrict__ asB, const float* __restrict__ adB,
    const int* __restrict__ rowPtr, const int* __restrict__ colSrc,
    const float* __restrict__ bias, ushort* __restrict__ hout, int applyElu) {
  const int n = (blockIdx.x * blockDim.x + threadIdx.x) >> 6;
  if (n >= NN) return;
  const int lane = threadIdx.x & 63;
  const int h = lane >> 4;
  const int ch = lane * 4;
  const float adn = adB[n * 4 + h];
  const float es = leaky(asB[n * 4 + h] + adn);   // self loop
  const int p0 = rowPtr[n], end = rowPtr[n + 1];

  // ---- pass A: running max (clamped duplicates are harmless for max) ----
  float m = es;
  for (int p = p0; p < end; p += 4) {
    const int i1 = (p + 1 < end) ? p + 1 : p;
    const int i2 = (p + 2 < end) ? p + 2 : p;
    const int i3 = (p + 3 < end) ? p + 3 : p;
    const int s0 = colSrc[p],  s1 = colSrc[i1];
    const int s2 = colSrc[i2], s3 = colSrc[i3];
    const float e0 = leaky(asB[s0 * 4 + h] + adn);
    const float e1 = leaky(asB[s1 * 4 + h] + adn);
    const float e2 = leaky(asB[s2 * 4 + h] + adn);
    const float e3 = leaky(asB[s3 * 4 + h] + adn);
    m = fmaxf(m, fmaxf(fmaxf(e0, e1), fmaxf(e2, e3)));
  }

  // ---- pass B: branch-free weighted gather ----
  float ws = __expf(es - m);
  float s = ws;
  ushort4 xv4 = *(const ushort4*)(xw + (size_t)n * 256 + ch);
  float4 acc = make_float4(ws * bf2f(xv4.x), ws * bf2f(xv4.y), ws * bf2f(xv4.z), ws * bf2f(xv4.w));
  for (int p = p0; p < end; p += 4) {
    const bool v1 = p + 1 < end, v2 = p + 2 < end, v3 = p + 3 < end;
    const int i1 = v1 ? p + 1 : p;
    const int i2 = v2 ? p + 2 : p;
    const int i3 = v3 ? p + 3 : p;
    const int s0 = colSrc[p],  s1 = colSrc[i1];
    const int s2 = colSrc[i2], s3 = colSrc[i3];
    const float e0 = leaky(asB[s0 * 4 + h] + adn);
    const float e1 = leaky(asB[s1 * 4 + h] + adn);
    const float e2 = leaky(asB[s2 * 4 + h] + adn);
    const float e3 = leaky(asB[s3 * 4 + h] + adn);
    const ushort4 u0 = *(const ushort4*)(xw + (size_t)s0 * 256 + ch);
    const ushort4 u1 = *(const ushort4*)(xw + (size_t)s1 * 256 + ch);
    const ushort4 u2 = *(const ushort4*)(xw + (size_t)s2 * 256 + ch);
    const ushort4 u3 = *(const ushort4*)(xw + (size_t)s3 * 256 + ch);
    const float w0 = __expf(e0 - m);
    const float w1 = v1 ? __expf(e1 - m) : 0.f;
    const float w2 = v2 ? __expf(e2 - m) : 0.f;
    const float w3 = v3 ? __expf(e3 - m) : 0.f;
    s += (w0 + w1) + (w2 + w3);
    acc.x += w0 * bf2f(u0.x) + w1 * bf2f(u1.x) + w2 * bf2f(u2.x) + w3 * bf2f(u3.x);
    acc.y += w0 * bf2f(u0.y) + w1 * bf2f(u1.y) + w2 * bf2f(u2.y) + w3 * bf2f(u3.y);
    acc.z += w0 * bf2f(u0.z) + w1 * bf2f(u1.z) + w2 * bf2f(u2.z) + w3 * bf2f(u3.z);
    acc.w += w0 * bf2f(u0.w) + w1 * bf2f(u1.w) + w2 * bf2f(u2.w) + w3 * bf2f(u3.w);
  }

  const float inv = 1.f / (s + 1e-16f);
  const float4 b4 = *(const float4*)(bias + ch);
  float o0 = acc.x * inv + b4.x, o1 = acc.y * inv + b4.y;
  float o2 = acc.z * inv + b4.z, o3 = acc.w * inv + b4.w;
  if (applyElu) {
    o0 = o0 > 0.f ? o0 : __expf(o0) - 1.f;
    o1 = o1 > 0.f ? o1 : __expf(o1) - 1.f;
    o2 = o2 > 0.f ? o2 : __expf(o2) - 1.f;
    o3 = o3 > 0.f ? o3 : __expf(o3) - 1.f;
  }
  ushort4 o4;
  o4.x = f2bf(o0); o4.y = f2bf(o1); o4.z = f2bf(o2); o4.w = f2bf(o3);
  *(ushort4*)(hout + (size_t)n * 256 + ch) = o4;
}

__global__ __launch_bounds__(256) void aggregate40_lsm_kernel(
    const ushort* __restrict__ xw, const float* __restrict__ asB, const float* __restrict__ adB,
    const int* __restrict__ rowPtr, const int* __restrict__ colSrc,
    const float* __restrict__ bias, float* __restrict__ out) {
  const int n = (blockIdx.x * blockDim.x + threadIdx.x) >> 6;
  if (n >= NN) return;
  const int lane = threadIdx.x & 63;
  const bool act = lane < 40;
  const float adn = adB[n];
  const float es = leaky(asB[n] + adn);
  const int p0 = rowPtr[n], end = rowPtr[n + 1];

  // ---- pass A: max ----
  float m = es;
  for (int p = p0; p < end; p += 4) {
    const int i1 = (p + 1 < end) ? p + 1 : p;
    const int i2 = (p + 2 < end) ? p + 2 : p;
    const int i3 = (p + 3 < end) ? p + 3 : p;
    const float e0 = leaky(asB[colSrc[p]] + adn);
    const float e1 = leaky(asB[colSrc[i1]] + adn);
    const float e2 = leaky(asB[colSrc[i2]] + adn);
    const float e3 = leaky(asB[colSrc[i3]] + adn);
    m = fmaxf(m, fmaxf(fmaxf(e0, e1), fmaxf(e2, e3)));
  }

  // ---- pass B ----
  float ws = __expf(es - m);
  float s = ws;
  float acc = act ? ws * bf2f(xw[(size_t)n * 40 + lane]) : 0.f;
  for (int p = p0; p < end; p += 4) {
    const bool v1 = p + 1 < end, v2 = p + 2 < end, v3 = p + 3 < end;
    const int i1 = v1 ? p + 1 : p;
    const int i2 = v2 ? p + 2 : p;
    const int i3 = v3 ? p + 3 : p;
    const int s0 = colSrc[p],  s1 = colSrc[i1];
    const int s2 = colSrc[i2], s3 = colSrc[i3];
    const float e0 = leaky(asB[s0] + adn);
    const float e1 = leaky(asB[s1] + adn);
    const float e2 = leaky(asB[s2] + adn);
    const float e3 = leaky(asB[s3] + adn);
    const float x0 = act ? bf2f(xw[(size_t)s0 * 40 + lane]) : 0.f;
    const float x1 = act ? bf2f(xw[(size_t)s1 * 40 + lane]) : 0.f;
    const float x2 = act ? bf2f(xw[(size_t)s2 * 40 + lane]) : 0.f;
    const float x3 = act ? bf2f(xw[(size_t)s3 * 40 + lane]) : 0.f;
    const float w0 = __expf(e0 - m);
    const float w1 = v1 ? __expf(e1 - m) : 0.f;
    const float w2 = v2 ? __expf(e2 - m) : 0.f;
    const float w3 = v3 ? __expf(e3 - m) : 0.f;
    s += (w0 + w1) + (w2 + w3);
    acc += w0 * x0 + w1 * x1 + w2 * x2 + w3 * x3;
  }

  float val = acc / (s + 1e-16f) + (act ? bias[lane] : 0.f);
  float v = act ? val : -1e30f;
  float mx = v;
#pragma unroll
  for (int o = 1; o < 64; o <<= 1) mx = fmaxf(mx, __shfl_xor(mx, o));
  float ex = act ? __expf(val - mx) : 0.f;
#pragma unroll
  for (int o = 1; o < 64; o <<= 1) ex += __shfl_xor(ex, o);
  if (act) out[(size_t)n * 40 + lane] = val - mx - __logf(ex);
}

// ---------------- launch ----------------

extern "C" void kernel_launch(void* const* d_in, const int* in_sizes, int n_in,
                              void* d_out, int out_size, void* d_ws, size_t ws_size,
                              hipStream_t stream) {
  const float* x   = (const float*)d_in[0];
  const int*   ei  = (const int*)d_in[1];
  const float* W1  = (const float*)d_in[2];
  const float* a1s = (const float*)d_in[3];
  const float* a1d = (const float*)d_in[4];
  const float* b1  = (const float*)d_in[5];
  const float* W2  = (const float*)d_in[6];
  const float* a2s = (const float*)d_in[7];
  const float* a2d = (const float*)d_in[8];
  const float* b2  = (const float*)d_in[9];
  const float* W3  = (const float*)d_in[10];
  const float* a3s = (const float*)d_in[11];
  const float* a3d = (const float*)d_in[12];
  const float* b3  = (const float*)d_in[13];
  float* out = (float*)d_out;

  char* w = (char*)d_ws;
  ushort* xbBuf = (ushort*)w;  w += (size_t)NN * 128 * 2;
  ushort* xwBuf = (ushort*)w;  w += (size_t)NN * 256 * 2;
  ushort* hBuf  = (ushort*)w;  w += (size_t)NN * 256 * 2;
  ushort* xw40  = (ushort*)w;  w += (size_t)NN * 40 * 2;
  float* asBuf  = (float*)w;   w += (size_t)NN * 4 * 4;
  float* adBuf  = (float*)w;   w += (size_t)NN * 4 * 4;
  ushort* Bf1   = (ushort*)w;  w += (size_t)17 * 4 * 512 * 2;
  ushort* Bf2   = (ushort*)w;  w += (size_t)17 * 8 * 512 * 2;
  ushort* Bf3   = (ushort*)w;  w += (size_t)3 * 8 * 512 * 2;
  int* counts   = (int*)w;     w += (size_t)NN * 4;
  int* cursor   = (int*)w;     w += (size_t)NN * 4;
  int* rowPtr   = (int*)w;     w += (size_t)(NN + 1) * 4;
  int* colSrc   = (int*)w;     w += (size_t)NE * 4;
  int* partial  = (int*)w;     w += (size_t)NN * 4;
  int* blockSums = (int*)w;    w += 64 * 4;

  const int nScanBlocks = (NN + 1023) / 1024;

  // CSR build
  hipMemsetAsync(counts, 0, (size_t)2 * NN * 4, stream);
  hist_kernel<<<(NE + 255) / 256, 256, 0, stream>>>(ei + NE, counts);
  scan1_kernel<<<nScanBlocks, 1024, 0, stream>>>(counts, partial, blockSums);
  scan2_kernel<<<1, 64, 0, stream>>>(blockSums, nScanBlocks);
  scan3_kernel<<<(NN + 255) / 256, 256, 0, stream>>>(partial, blockSums, rowPtr);
  fill_kernel<<<(NE + 255) / 256, 256, 0, stream>>>(ei, ei + NE, rowPtr, cursor, colSrc);

  // x -> bf16
  f2bf_kernel<<<(NN * 128 / 4 + 255) / 256, 256, 0, stream>>>(x, xbBuf, NN * 128 / 4);

  // pre-fragment weights (+ fused logit columns)
  prefrag_kernel<<<(17 * 4 * 512 + 255) / 256, 256, 0, stream>>>(W1, a1s, a1d, Bf1, 128, 256, 4, 64, 17);
  prefrag_kernel<<<(17 * 8 * 512 + 255) / 256, 256, 0, stream>>>(W2, a2s, a2d, Bf2, 256, 256, 4, 64, 17);
  prefrag_kernel<<<(3 * 8 * 512 + 255) / 256, 256, 0, stream>>>(W3, a3s, a3d, Bf3, 256, 40, 1, 40, 3);

  const int gemmBlocks = (NN + 63) / 64;
  const int nodeBlocks = NN / 4;

  // layer 1: 128 -> 4x64
  gemm_mfma_kernel<17><<<gemmBlocks, 256, 0, stream>>>(xbBuf, Bf1, xwBuf, asBuf, adBuf, 128, 256, 4);
  aggregate256_kernel<<<nodeBlocks, 256, 0, stream>>>(xwBuf, asBuf, adBuf, rowPtr, colSrc, b1, hBuf, 1);

  // layer 2: 256 -> 4x64
  gemm_mfma_kernel<17><<<gemmBlocks, 256, 0, stream>>>(hBuf, Bf2, xwBuf, asBuf, adBuf, 256, 256, 4);
  aggregate256_kernel<<<nodeBlocks, 256, 0, stream>>>(xwBuf, asBuf, adBuf, rowPtr, colSrc, b2, hBuf, 1);

  // layer 3: 256 -> 40 (+ log_softmax)
  gemm_mfma_kernel<3><<<gemmBlocks, 256, 0, stream>>>(hBuf, Bf3, xw40, asBuf, adBuf, 256, 40, 1);
  aggregate40_lsm_kernel<<<nodeBlocks, 256, 0, stream>>>(xw40, asBuf, adBuf, rowPtr, colSrc, b3, out);
}

// Round 4
// 532.843 us; speedup vs baseline: 1.3940x; 1.0775x over previous
//
#include <hip/hip_runtime.h>
#include <hip/hip_bf16.h>

#define NN 50000
#define NE 800000

using bf16x8 = __attribute__((ext_vector_type(8))) short;
using f32x4  = __attribute__((ext_vector_type(4))) float;

__device__ __forceinline__ ushort f2bf(float f) {
  uint x = __float_as_uint(f);
  return (ushort)((x + 0x7FFFu + ((x >> 16) & 1u)) >> 16);
}
__device__ __forceinline__ float bf2f(ushort u) {
  return __uint_as_float(((uint)u) << 16);
}
__device__ __forceinline__ float leaky(float x) { return fmaxf(x, 0.2f * x); }

// ---------------- CSR build ----------------

__global__ __launch_bounds__(256) void hist_kernel(const int* __restrict__ dst,
                                                   int* __restrict__ counts) {
  int e = blockIdx.x * 256 + threadIdx.x;
  if (e < NE) atomicAdd(&counts[dst[e]], 1);
}

__global__ __launch_bounds__(1024) void scan1_kernel(const int* __restrict__ counts,
                                                     int* __restrict__ partial,
                                                     int* __restrict__ blockSums) {
  __shared__ int sm[1024];
  int i = blockIdx.x * 1024 + threadIdx.x;
  sm[threadIdx.x] = (i < NN) ? counts[i] : 0;
  __syncthreads();
  for (int off = 1; off < 1024; off <<= 1) {
    int t = (threadIdx.x >= off) ? sm[threadIdx.x - off] : 0;
    __syncthreads();
    sm[threadIdx.x] += t;
    __syncthreads();
  }
  if (i < NN) partial[i] = sm[threadIdx.x];
  if (threadIdx.x == 1023) blockSums[blockIdx.x] = sm[1023];
}

__global__ void scan2_kernel(int* blockSums, int nb) {
  if (threadIdx.x == 0) {
    int run = 0;
    for (int b = 0; b < nb; ++b) { int v = blockSums[b]; blockSums[b] = run; run += v; }
  }
}

__global__ __launch_bounds__(256) void scan3_kernel(const int* __restrict__ partial,
                                                    const int* __restrict__ blockOffs,
                                                    int* __restrict__ rowPtr) {
  int i = blockIdx.x * 256 + threadIdx.x;
  if (i < NN) {
    rowPtr[i + 1] = partial[i] + blockOffs[i >> 10];
    if (i == 0) rowPtr[0] = 0;
  }
}

__global__ __launch_bounds__(256) void fill_kernel(const int* __restrict__ srcArr,
                                                   const int* __restrict__ dstArr,
                                                   const int* __restrict__ rowPtr,
                                                   int* __restrict__ cursor,
                                                   int* __restrict__ colSrc) {
  int e = blockIdx.x * 256 + threadIdx.x;
  if (e < NE) {
    int d = dstArr[e];
    int p = rowPtr[d] + atomicAdd(&cursor[d], 1);
    colSrc[p] = srcArr[e];
  }
}

// ---------------- pre-fragment B' = [W | W@att_s | W@att_d | 0] into MFMA lane order ----------------

__global__ __launch_bounds__(256) void prefrag_kernel(const float* __restrict__ W,
                                                      const float* __restrict__ atS,
                                                      const float* __restrict__ atD,
                                                      ushort* __restrict__ Bf,
                                                      int K, int Mout, int nh, int Cdim, int NCT) {
  int idx = blockIdx.x * 256 + threadIdx.x;
  const int KC = K >> 5;
  const int total = NCT * KC * 512;
  if (idx >= total) return;
  int i = idx & 7;
  int lane = (idx >> 3) & 63;
  int kc = (idx >> 9) % KC;
  int ct = idx / (KC * 512);
  int k = kc * 32 + (lane >> 4) * 8 + i;
  int col = ct * 16 + (lane & 15);
  float v = 0.f;
  if (col < Mout) {
    v = W[(size_t)k * Mout + col];
  } else if (col < Mout + nh) {
    int h = col - Mout; float s = 0.f;
    for (int c = 0; c < Cdim; ++c) s += W[(size_t)k * Mout + h * Cdim + c] * atS[h * Cdim + c];
    v = s;
  } else if (col < Mout + 2 * nh) {
    int h = col - Mout - nh; float s = 0.f;
    for (int c = 0; c < Cdim; ++c) s += W[(size_t)k * Mout + h * Cdim + c] * atD[h * Cdim + c];
    v = s;
  }
  Bf[idx] = f2bf(v);
}

// ---------------- LDS-free bf16 MFMA GEMM with fused logit columns ----------------
// AF32: A is fp32 (converted on the fly) else bf16.

template <int NCT, bool AF32>
__global__ __launch_bounds__(256) void gemm_mfma_kernel(const void* __restrict__ Araw,
                                                        const ushort* __restrict__ Bf,
                                                        ushort* __restrict__ xw,
                                                        float* __restrict__ asB,
                                                        float* __restrict__ adB,
                                                        int K, int Mout, int nh) {
  const int lane = threadIdx.x & 63;
  const int w = threadIdx.x >> 6;
  const int rowBase = blockIdx.x * 64 + w * 16;
  if (rowBase >= NN) return;
  const int KC = K >> 5;
  const int arow = rowBase + (lane & 15);
  const int koff = (lane >> 4) * 8;
  f32x4 acc[NCT];
#pragma unroll
  for (int ct = 0; ct < NCT; ++ct) acc[ct] = (f32x4){0.f, 0.f, 0.f, 0.f};
  for (int kc = 0; kc < KC; ++kc) {
    bf16x8 af;
    if (AF32) {
      const float* ap = (const float*)Araw + (size_t)arow * K + koff + kc * 32;
      float4 p0 = *(const float4*)ap;
      float4 p1 = *(const float4*)(ap + 4);
      af[0] = (short)f2bf(p0.x); af[1] = (short)f2bf(p0.y);
      af[2] = (short)f2bf(p0.z); af[3] = (short)f2bf(p0.w);
      af[4] = (short)f2bf(p1.x); af[5] = (short)f2bf(p1.y);
      af[6] = (short)f2bf(p1.z); af[7] = (short)f2bf(p1.w);
    } else {
      const ushort* ap = (const ushort*)Araw + (size_t)arow * K + koff + kc * 32;
      af = *reinterpret_cast<const bf16x8*>(ap);
    }
    const ushort* bp = Bf + (size_t)kc * 512 + lane * 8;
#pragma unroll
    for (int ct = 0; ct < NCT; ++ct) {
      bf16x8 bfr = *reinterpret_cast<const bf16x8*>(bp + (size_t)ct * KC * 512);
      acc[ct] = __builtin_amdgcn_mfma_f32_16x16x32_bf16(af, bfr, acc[ct], 0, 0, 0);
    }
  }
  const int colL = lane & 15;
  const int rquad = (lane >> 4) * 4;
#pragma unroll
  for (int ct = 0; ct < NCT; ++ct) {
    const int col = ct * 16 + colL;
#pragma unroll
    for (int r = 0; r < 4; ++r) {
      const int row = rowBase + rquad + r;
      const float v = acc[ct][r];
      if (col < Mout) {
        xw[(size_t)row * Mout + col] = f2bf(v);
      } else if (col < Mout + nh) {
        asB[(size_t)row * nh + (col - Mout)] = v;
      } else if (col < Mout + 2 * nh) {
        adB[(size_t)row * nh + (col - Mout - nh)] = v;
      }
    }
  }
}

// ---------------- aggregation v2: wave/node, lane-per-edge softmax + weighted gather ----------------

__global__ __launch_bounds__(256) void aggregate256_kernel(
    const ushort* __restrict__ xw, const float* __restrict__ asB, const float* __restrict__ adB,
    const int* __restrict__ rowPtr, const int* __restrict__ colSrc,
    const float* __restrict__ bias, ushort* __restrict__ hout, int applyElu) {
  __shared__ int   lsrc[4][64];
  __shared__ float lw[4][256];
  const int n = (blockIdx.x * blockDim.x + threadIdx.x) >> 6;
  if (n >= NN) return;
  const int lane = threadIdx.x & 63;
  const int wv = (threadIdx.x >> 6) & 3;
  const int h = lane >> 4;
  const int ch = lane * 4;
  const int p0 = rowPtr[n], deg = rowPtr[n + 1] - p0;
  const float4 ad4 = *(const float4*)(adB + n * 4);
  const float4 as4 = *(const float4*)(asB + n * 4);
  float4 m;  // running max per head (same in all lanes)
  m.x = leaky(as4.x + ad4.x); m.y = leaky(as4.y + ad4.y);
  m.z = leaky(as4.z + ad4.z); m.w = leaky(as4.w + ad4.w);
  float4 s = make_float4(1.f, 1.f, 1.f, 1.f);  // self weight = exp(0)
  ushort4 xv4 = *(const ushort4*)(xw + (size_t)n * 256 + ch);
  float4 acc = make_float4(bf2f(xv4.x), bf2f(xv4.y), bf2f(xv4.z), bf2f(xv4.w));

  for (int c0 = 0; c0 < deg; c0 += 64) {
    const int e = c0 + lane;
    const bool valid = e < deg;
    const int src = valid ? colSrc[p0 + e] : n;
    const float4 a4 = *(const float4*)(asB + src * 4);
    float4 ev;
    ev.x = valid ? leaky(a4.x + ad4.x) : -3.0e38f;
    ev.y = valid ? leaky(a4.y + ad4.y) : -3.0e38f;
    ev.z = valid ? leaky(a4.z + ad4.z) : -3.0e38f;
    ev.w = valid ? leaky(a4.w + ad4.w) : -3.0e38f;
    // chunk max reduce
    float4 mc = ev;
#pragma unroll
    for (int o = 1; o < 64; o <<= 1) {
      mc.x = fmaxf(mc.x, __shfl_xor(mc.x, o));
      mc.y = fmaxf(mc.y, __shfl_xor(mc.y, o));
      mc.z = fmaxf(mc.z, __shfl_xor(mc.z, o));
      mc.w = fmaxf(mc.w, __shfl_xor(mc.w, o));
    }
    float4 m2;
    m2.x = fmaxf(m.x, mc.x); m2.y = fmaxf(m.y, mc.y);
    m2.z = fmaxf(m.z, mc.z); m2.w = fmaxf(m.w, mc.w);
    float4 sc;
    sc.x = __expf(m.x - m2.x); sc.y = __expf(m.y - m2.y);
    sc.z = __expf(m.z - m2.z); sc.w = __expf(m.w - m2.w);
    const float msc = (h == 0) ? sc.x : (h == 1) ? sc.y : (h == 2) ? sc.z : sc.w;
    acc.x *= msc; acc.y *= msc; acc.z *= msc; acc.w *= msc;
    float4 w4;
    w4.x = valid ? __expf(ev.x - m2.x) : 0.f;
    w4.y = valid ? __expf(ev.y - m2.y) : 0.f;
    w4.z = valid ? __expf(ev.z - m2.z) : 0.f;
    w4.w = valid ? __expf(ev.w - m2.w) : 0.f;
    lsrc[wv][lane] = src;
    *(float4*)&lw[wv][lane * 4] = make_float4(w4.x, w4.y, w4.z, w4.w);
    float4 ss = w4;
#pragma unroll
    for (int o = 1; o < 64; o <<= 1) {
      ss.x += __shfl_xor(ss.x, o);
      ss.y += __shfl_xor(ss.y, o);
      ss.z += __shfl_xor(ss.z, o);
      ss.w += __shfl_xor(ss.w, o);
    }
    s.x = s.x * sc.x + ss.x; s.y = s.y * sc.y + ss.y;
    s.z = s.z * sc.z + ss.z; s.w = s.w * sc.w + ss.w;
    m = m2;
    // ---- weighted gather over this chunk ----
    const int cd = min(64, deg - c0);
    for (int j = 0; j < cd; j += 4) {
      const int s0 = lsrc[wv][j + 0], s1 = lsrc[wv][j + 1];
      const int s2 = lsrc[wv][j + 2], s3 = lsrc[wv][j + 3];
      const float w0 = lw[wv][(j + 0) * 4 + h];
      const float w1 = lw[wv][(j + 1) * 4 + h];
      const float w2 = lw[wv][(j + 2) * 4 + h];
      const float w3 = lw[wv][(j + 3) * 4 + h];
      const ushort4 u0 = *(const ushort4*)(xw + (size_t)s0 * 256 + ch);
      const ushort4 u1 = *(const ushort4*)(xw + (size_t)s1 * 256 + ch);
      const ushort4 u2 = *(const ushort4*)(xw + (size_t)s2 * 256 + ch);
      const ushort4 u3 = *(const ushort4*)(xw + (size_t)s3 * 256 + ch);
      acc.x += w0 * bf2f(u0.x) + w1 * bf2f(u1.x) + w2 * bf2f(u2.x) + w3 * bf2f(u3.x);
      acc.y += w0 * bf2f(u0.y) + w1 * bf2f(u1.y) + w2 * bf2f(u2.y) + w3 * bf2f(u3.y);
      acc.z += w0 * bf2f(u0.z) + w1 * bf2f(u1.z) + w2 * bf2f(u2.z) + w3 * bf2f(u3.z);
      acc.w += w0 * bf2f(u0.w) + w1 * bf2f(u1.w) + w2 * bf2f(u2.w) + w3 * bf2f(u3.w);
    }
  }

  const float sh = (h == 0) ? s.x : (h == 1) ? s.y : (h == 2) ? s.z : s.w;
  const float inv = 1.f / (sh + 1e-16f);
  const float4 b4 = *(const float4*)(bias + ch);
  float o0 = acc.x * inv + b4.x, o1 = acc.y * inv + b4.y;
  float o2 = acc.z * inv + b4.z, o3 = acc.w * inv + b4.w;
  if (applyElu) {
    o0 = o0 > 0.f ? o0 : __expf(o0) - 1.f;
    o1 = o1 > 0.f ? o1 : __expf(o1) - 1.f;
    o2 = o2 > 0.f ? o2 : __expf(o2) - 1.f;
    o3 = o3 > 0.f ? o3 : __expf(o3) - 1.f;
  }
  ushort4 o4;
  o4.x = f2bf(o0); o4.y = f2bf(o1); o4.z = f2bf(o2); o4.w = f2bf(o3);
  *(ushort4*)(hout + (size_t)n * 256 + ch) = o4;
}

__global__ __launch_bounds__(256) void aggregate40_lsm_kernel(
    const ushort* __restrict__ xw, const float* __restrict__ asB, const float* __restrict__ adB,
    const int* __restrict__ rowPtr, const int* __restrict__ colSrc,
    const float* __restrict__ bias, float* __restrict__ out) {
  __shared__ int   lsrc[4][64];
  __shared__ float lw[4][64];
  const int n = (blockIdx.x * blockDim.x + threadIdx.x) >> 6;
  if (n >= NN) return;
  const int lane = threadIdx.x & 63;
  const int wv = (threadIdx.x >> 6) & 3;
  const bool act = lane < 40;
  const int p0 = rowPtr[n], deg = rowPtr[n + 1] - p0;
  const float adn = adB[n];
  float m = leaky(asB[n] + adn);
  float s = 1.f;
  float acc = act ? bf2f(xw[(size_t)n * 40 + lane]) : 0.f;

  for (int c0 = 0; c0 < deg; c0 += 64) {
    const int e = c0 + lane;
    const bool valid = e < deg;
    const int src = valid ? colSrc[p0 + e] : n;
    const float a = asB[src];
    float ev = valid ? leaky(a + adn) : -3.0e38f;
    float mc = ev;
#pragma unroll
    for (int o = 1; o < 64; o <<= 1) mc = fmaxf(mc, __shfl_xor(mc, o));
    const float m2 = fmaxf(m, mc);
    const float scl = __expf(m - m2);
    acc *= scl;
    float wv_ = valid ? __expf(ev - m2) : 0.f;
    lsrc[wv][lane] = src;
    lw[wv][lane] = wv_;
    float ss = wv_;
#pragma unroll
    for (int o = 1; o < 64; o <<= 1) ss += __shfl_xor(ss, o);
    s = s * scl + ss;
    m = m2;
    const int cd = min(64, deg - c0);
    for (int j = 0; j < cd; j += 4) {
      const int s0 = lsrc[wv][j + 0], s1 = lsrc[wv][j + 1];
      const int s2 = lsrc[wv][j + 2], s3 = lsrc[wv][j + 3];
      const float w0 = lw[wv][j + 0], w1 = lw[wv][j + 1];
      const float w2 = lw[wv][j + 2], w3 = lw[wv][j + 3];
      const float x0 = act ? bf2f(xw[(size_t)s0 * 40 + lane]) : 0.f;
      const float x1 = act ? bf2f(xw[(size_t)s1 * 40 + lane]) : 0.f;
      const float x2 = act ? bf2f(xw[(size_t)s2 * 40 + lane]) : 0.f;
      const float x3 = act ? bf2f(xw[(size_t)s3 * 40 + lane]) : 0.f;
      acc += w0 * x0 + w1 * x1 + w2 * x2 + w3 * x3;
    }
  }

  float val = acc / (s + 1e-16f) + (act ? bias[lane] : 0.f);
  float v = act ? val : -1e30f;
  float mx = v;
#pragma unroll
  for (int o = 1; o < 64; o <<= 1) mx = fmaxf(mx, __shfl_xor(mx, o));
  float ex = act ? __expf(val - mx) : 0.f;
#pragma unroll
  for (int o = 1; o < 64; o <<= 1) ex += __shfl_xor(ex, o);
  if (act) out[(size_t)n * 40 + lane] = val - mx - __logf(ex);
}

// ---------------- launch ----------------

extern "C" void kernel_launch(void* const* d_in, const int* in_sizes, int n_in,
                              void* d_out, int out_size, void* d_ws, size_t ws_size,
                              hipStream_t stream) {
  const float* x   = (const float*)d_in[0];
  const int*   ei  = (const int*)d_in[1];
  const float* W1  = (const float*)d_in[2];
  const float* a1s = (const float*)d_in[3];
  const float* a1d = (const float*)d_in[4];
  const float* b1  = (const float*)d_in[5];
  const float* W2  = (const float*)d_in[6];
  const float* a2s = (const float*)d_in[7];
  const float* a2d = (const float*)d_in[8];
  const float* b2  = (const float*)d_in[9];
  const float* W3  = (const float*)d_in[10];
  const float* a3s = (const float*)d_in[11];
  const float* a3d = (const float*)d_in[12];
  const float* b3  = (const float*)d_in[13];
  float* out = (float*)d_out;

  char* w = (char*)d_ws;
  ushort* xwBuf = (ushort*)w;  w += (size_t)NN * 256 * 2;
  ushort* hBuf  = (ushort*)w;  w += (size_t)NN * 256 * 2;
  ushort* xw40  = (ushort*)w;  w += (size_t)NN * 40 * 2;
  float* asBuf  = (float*)w;   w += (size_t)NN * 4 * 4;
  float* adBuf  = (float*)w;   w += (size_t)NN * 4 * 4;
  ushort* Bf1   = (ushort*)w;  w += (size_t)17 * 4 * 512 * 2;
  ushort* Bf2   = (ushort*)w;  w += (size_t)17 * 8 * 512 * 2;
  ushort* Bf3   = (ushort*)w;  w += (size_t)3 * 8 * 512 * 2;
  int* counts   = (int*)w;     w += (size_t)NN * 4;
  int* cursor   = (int*)w;     w += (size_t)NN * 4;
  int* rowPtr   = (int*)w;     w += (size_t)(NN + 1) * 4;
  int* colSrc   = (int*)w;     w += (size_t)NE * 4;
  int* partial  = (int*)w;     w += (size_t)NN * 4;
  int* blockSums = (int*)w;    w += 64 * 4;

  const int nScanBlocks = (NN + 1023) / 1024;

  // CSR build
  hipMemsetAsync(counts, 0, (size_t)2 * NN * 4, stream);
  hist_kernel<<<(NE + 255) / 256, 256, 0, stream>>>(ei + NE, counts);
  scan1_kernel<<<nScanBlocks, 1024, 0, stream>>>(counts, partial, blockSums);
  scan2_kernel<<<1, 64, 0, stream>>>(blockSums, nScanBlocks);
  scan3_kernel<<<(NN + 255) / 256, 256, 0, stream>>>(partial, blockSums, rowPtr);
  fill_kernel<<<(NE + 255) / 256, 256, 0, stream>>>(ei, ei + NE, rowPtr, cursor, colSrc);

  // pre-fragment weights (+ fused logit columns)
  prefrag_kernel<<<(17 * 4 * 512 + 255) / 256, 256, 0, stream>>>(W1, a1s, a1d, Bf1, 128, 256, 4, 64, 17);
  prefrag_kernel<<<(17 * 8 * 512 + 255) / 256, 256, 0, stream>>>(W2, a2s, a2d, Bf2, 256, 256, 4, 64, 17);
  prefrag_kernel<<<(3 * 8 * 512 + 255) / 256, 256, 0, stream>>>(W3, a3s, a3d, Bf3, 256, 40, 1, 40, 3);

  const int gemmBlocks = (NN + 63) / 64;
  const int nodeBlocks = NN / 4;

  // layer 1: 128 -> 4x64 (fp32 A converted on the fly)
  gemm_mfma_kernel<17, true><<<gemmBlocks, 256, 0, stream>>>(x, Bf1, xwBuf, asBuf, adBuf, 128, 256, 4);
  aggregate256_kernel<<<nodeBlocks, 256, 0, stream>>>(xwBuf, asBuf, adBuf, rowPtr, colSrc, b1, hBuf, 1);

  // layer 2: 256 -> 4x64
  gemm_mfma_kernel<17, false><<<gemmBlocks, 256, 0, stream>>>(hBuf, Bf2, xwBuf, asBuf, adBuf, 256, 256, 4);
  aggregate256_kernel<<<nodeBlocks, 256, 0, stream>>>(xwBuf, asBuf, adBuf, rowPtr, colSrc, b2, hBuf, 1);

  // layer 3: 256 -> 40 (+ log_softmax)
  gemm_mfma_kernel<3, false><<<gemmBlocks, 256, 0, stream>>>(hBuf, Bf3, xw40, asBuf, adBuf, 256, 40, 1);
  aggregate40_lsm_kernel<<<nodeBlocks, 256, 0, stream>>>(xw40, asBuf, adBuf, rowPtr, colSrc, b3, out);
}

// Round 5
// 472.170 us; speedup vs baseline: 1.5731x; 1.1285x over previous
//
#include <hip/hip_runtime.h>
#include <hip/hip_bf16.h>

#define NN 50000
#define NE 800000

using bf16x8 = __attribute__((ext_vector_type(8))) short;
using f32x4  = __attribute__((ext_vector_type(4))) float;

__device__ __forceinline__ ushort f2bf(float f) {
  uint x = __float_as_uint(f);
  return (ushort)((x + 0x7FFFu + ((x >> 16) & 1u)) >> 16);
}
__device__ __forceinline__ float bf2f(ushort u) {
  return __uint_as_float(((uint)u) << 16);
}
__device__ __forceinline__ float leaky(float x) { return fmaxf(x, 0.2f * x); }

// async global->LDS, 16B per lane; LDS dest is wave-uniform base + lane*16
__device__ __forceinline__ void gload_lds16(const void* g, void* l) {
  __builtin_amdgcn_global_load_lds(
      (const __attribute__((address_space(1))) unsigned int*)g,
      (__attribute__((address_space(3))) unsigned int*)l, 16, 0, 0);
}

// ---------------- CSR build ----------------

__global__ __launch_bounds__(256) void hist_kernel(const int* __restrict__ dst,
                                                   int* __restrict__ counts) {
  int e = blockIdx.x * 256 + threadIdx.x;
  if (e < NE) atomicAdd(&counts[dst[e]], 1);
}

__global__ __launch_bounds__(1024) void scan1_kernel(const int* __restrict__ counts,
                                                     int* __restrict__ partial,
                                                     int* __restrict__ blockSums) {
  __shared__ int sm[1024];
  int i = blockIdx.x * 1024 + threadIdx.x;
  sm[threadIdx.x] = (i < NN) ? counts[i] : 0;
  __syncthreads();
  for (int off = 1; off < 1024; off <<= 1) {
    int t = (threadIdx.x >= off) ? sm[threadIdx.x - off] : 0;
    __syncthreads();
    sm[threadIdx.x] += t;
    __syncthreads();
  }
  if (i < NN) partial[i] = sm[threadIdx.x];
  if (threadIdx.x == 1023) blockSums[blockIdx.x] = sm[1023];
}

__global__ void scan2_kernel(int* blockSums, int nb) {
  if (threadIdx.x == 0) {
    int run = 0;
    for (int b = 0; b < nb; ++b) { int v = blockSums[b]; blockSums[b] = run; run += v; }
  }
}

__global__ __launch_bounds__(256) void scan3_kernel(const int* __restrict__ partial,
                                                    const int* __restrict__ blockOffs,
                                                    int* __restrict__ rowPtr) {
  int i = blockIdx.x * 256 + threadIdx.x;
  if (i < NN) {
    rowPtr[i + 1] = partial[i] + blockOffs[i >> 10];
    if (i == 0) rowPtr[0] = 0;
  }
}

__global__ __launch_bounds__(256) void fill_kernel(const int* __restrict__ srcArr,
                                                   const int* __restrict__ dstArr,
                                                   const int* __restrict__ rowPtr,
                                                   int* __restrict__ cursor,
                                                   int* __restrict__ colSrc) {
  int e = blockIdx.x * 256 + threadIdx.x;
  if (e < NE) {
    int d = dstArr[e];
    int p = rowPtr[d] + atomicAdd(&cursor[d], 1);
    colSrc[p] = srcArr[e];
  }
}

// ---------------- pre-fragment B' = [W | W@att_s | W@att_d | 0] into MFMA lane order ----------------
// Bf flat index = (ct*KC + kc)*512 + lane*8 + i  <->  B'[kc*32 + (lane>>4)*8 + i][ct*16 + (lane&15)]

__global__ __launch_bounds__(256) void prefrag_kernel(const float* __restrict__ W,
                                                      const float* __restrict__ atS,
                                                      const float* __restrict__ atD,
                                                      ushort* __restrict__ Bf,
                                                      int K, int Mout, int nh, int Cdim, int NCT) {
  int idx = blockIdx.x * 256 + threadIdx.x;
  const int KC = K >> 5;
  const int total = NCT * KC * 512;
  if (idx >= total) return;
  int i = idx & 7;
  int lane = (idx >> 3) & 63;
  int kc = (idx >> 9) % KC;
  int ct = idx / (KC * 512);
  int k = kc * 32 + (lane >> 4) * 8 + i;
  int col = ct * 16 + (lane & 15);
  float v = 0.f;
  if (col < Mout) {
    v = W[(size_t)k * Mout + col];
  } else if (col < Mout + nh) {
    int h = col - Mout; float s = 0.f;
    for (int c = 0; c < Cdim; ++c) s += W[(size_t)k * Mout + h * Cdim + c] * atS[h * Cdim + c];
    v = s;
  } else if (col < Mout + 2 * nh) {
    int h = col - Mout - nh; float s = 0.f;
    for (int c = 0; c < Cdim; ++c) s += W[(size_t)k * Mout + h * Cdim + c] * atD[h * Cdim + c];
    v = s;
  }
  Bf[idx] = f2bf(v);
}

// ---------------- bf16 MFMA GEMM: LDS-staged B (double-buffered global_load_lds) ----------------
// Block = 4 waves, 64 rows. B fragments shared by all waves via LDS.

template <int NCT, int KC, bool AF32>
__global__ __launch_bounds__(256) void gemm_mfma_kernel(const void* __restrict__ Araw,
                                                        const ushort* __restrict__ Bf,
                                                        ushort* __restrict__ xw,
                                                        float* __restrict__ asB,
                                                        float* __restrict__ adB,
                                                        int Mout, int nh) {
  __shared__ __align__(16) ushort sB[2][NCT * 512];
  constexpr int K = KC * 32;
  const int lane = threadIdx.x & 63;
  const int w = threadIdx.x >> 6;
  const int rowBase = blockIdx.x * 64 + w * 16;
  const int arow = min(rowBase + (lane & 15), NN - 1);   // clamp; no early return (barriers!)
  const int koff = (lane >> 4) * 8;
  f32x4 acc[NCT];
#pragma unroll
  for (int ct = 0; ct < NCT; ++ct) acc[ct] = (f32x4){0.f, 0.f, 0.f, 0.f};

  // prologue: stage kc=0 into buf 0 (wave w takes chunks ct = w, w+4, ...)
#pragma unroll
  for (int ct0 = 0; ct0 < NCT; ++ct0) {
    if ((ct0 & 3) == w)
      gload_lds16(Bf + (((size_t)ct0 * KC) << 9) + lane * 8, &sB[0][ct0 * 512]);
  }
  __syncthreads();

#pragma unroll
  for (int kc = 0; kc < KC; ++kc) {
    const int nb = kc & 1;
    if (kc + 1 < KC) {
#pragma unroll
      for (int ct0 = 0; ct0 < NCT; ++ct0) {
        if ((ct0 & 3) == w)
          gload_lds16(Bf + (((size_t)ct0 * KC + kc + 1) << 9) + lane * 8,
                      &sB[nb ^ 1][ct0 * 512]);
      }
    }
    bf16x8 af;
    if constexpr (AF32) {
      const float* ap = (const float*)Araw + (size_t)arow * K + koff + kc * 32;
      float4 p0 = *(const float4*)ap;
      float4 p1 = *(const float4*)(ap + 4);
      af[0] = (short)f2bf(p0.x); af[1] = (short)f2bf(p0.y);
      af[2] = (short)f2bf(p0.z); af[3] = (short)f2bf(p0.w);
      af[4] = (short)f2bf(p1.x); af[5] = (short)f2bf(p1.y);
      af[6] = (short)f2bf(p1.z); af[7] = (short)f2bf(p1.w);
    } else {
      const ushort* ap = (const ushort*)Araw + (size_t)arow * K + koff + kc * 32;
      af = *reinterpret_cast<const bf16x8*>(ap);
    }
#pragma unroll
    for (int ct = 0; ct < NCT; ++ct) {
      bf16x8 bfr = *reinterpret_cast<const bf16x8*>(&sB[nb][ct * 512 + lane * 8]);
      acc[ct] = __builtin_amdgcn_mfma_f32_16x16x32_bf16(af, bfr, acc[ct], 0, 0, 0);
    }
    __syncthreads();   // drains vmcnt (prefetch DMA) + orders buffer reuse
  }

  // epilogue: D mapping col = lane&15, row = (lane>>4)*4 + r  (row-guarded!)
  const int colL = lane & 15;
  const int rquad = (lane >> 4) * 4;
#pragma unroll
  for (int ct = 0; ct < NCT; ++ct) {
    const int col = ct * 16 + colL;
#pragma unroll
    for (int r = 0; r < 4; ++r) {
      const int row = rowBase + rquad + r;
      if (row < NN) {
        const float v = acc[ct][r];
        if (col < Mout) {
          xw[(size_t)row * Mout + col] = f2bf(v);
        } else if (col < Mout + nh) {
          asB[(size_t)row * nh + (col - Mout)] = v;
        } else if (col < Mout + 2 * nh) {
          adB[(size_t)row * nh + (col - Mout - nh)] = v;
        }
      }
    }
  }
}

// ---------------- aggregation: wave/node, lane-per-edge softmax + weighted gather ----------------

__global__ __launch_bounds__(256) void aggregate256_kernel(
    const ushort* __restrict__ xw, const float* __restrict__ asB, const float* __restrict__ adB,
    const int* __restrict__ rowPtr, const int* __restrict__ colSrc,
    const float* __restrict__ bias, ushort* __restrict__ hout, int applyElu) {
  __shared__ int   lsrc[4][64];
  __shared__ float lw[4][256];
  const int n = (blockIdx.x * blockDim.x + threadIdx.x) >> 6;
  if (n >= NN) return;
  const int lane = threadIdx.x & 63;
  const int wv = (threadIdx.x >> 6) & 3;
  const int h = lane >> 4;
  const int ch = lane * 4;
  const int p0 = rowPtr[n], deg = rowPtr[n + 1] - p0;
  const float4 ad4 = *(const float4*)(adB + n * 4);
  const float4 as4 = *(const float4*)(asB + n * 4);
  float4 m;
  m.x = leaky(as4.x + ad4.x); m.y = leaky(as4.y + ad4.y);
  m.z = leaky(as4.z + ad4.z); m.w = leaky(as4.w + ad4.w);
  float4 s = make_float4(1.f, 1.f, 1.f, 1.f);
  ushort4 xv4 = *(const ushort4*)(xw + (size_t)n * 256 + ch);
  float4 acc = make_float4(bf2f(xv4.x), bf2f(xv4.y), bf2f(xv4.z), bf2f(xv4.w));

  for (int c0 = 0; c0 < deg; c0 += 64) {
    const int e = c0 + lane;
    const bool valid = e < deg;
    const int src = valid ? colSrc[p0 + e] : n;
    const float4 a4 = *(const float4*)(asB + src * 4);
    float4 ev;
    ev.x = valid ? leaky(a4.x + ad4.x) : -3.0e38f;
    ev.y = valid ? leaky(a4.y + ad4.y) : -3.0e38f;
    ev.z = valid ? leaky(a4.z + ad4.z) : -3.0e38f;
    ev.w = valid ? leaky(a4.w + ad4.w) : -3.0e38f;
    float4 mc = ev;
#pragma unroll
    for (int o = 1; o < 64; o <<= 1) {
      mc.x = fmaxf(mc.x, __shfl_xor(mc.x, o));
      mc.y = fmaxf(mc.y, __shfl_xor(mc.y, o));
      mc.z = fmaxf(mc.z, __shfl_xor(mc.z, o));
      mc.w = fmaxf(mc.w, __shfl_xor(mc.w, o));
    }
    float4 m2;
    m2.x = fmaxf(m.x, mc.x); m2.y = fmaxf(m.y, mc.y);
    m2.z = fmaxf(m.z, mc.z); m2.w = fmaxf(m.w, mc.w);
    float4 sc;
    sc.x = __expf(m.x - m2.x); sc.y = __expf(m.y - m2.y);
    sc.z = __expf(m.z - m2.z); sc.w = __expf(m.w - m2.w);
    const float msc = (h == 0) ? sc.x : (h == 1) ? sc.y : (h == 2) ? sc.z : sc.w;
    acc.x *= msc; acc.y *= msc; acc.z *= msc; acc.w *= msc;
    float4 w4;
    w4.x = valid ? __expf(ev.x - m2.x) : 0.f;
    w4.y = valid ? __expf(ev.y - m2.y) : 0.f;
    w4.z = valid ? __expf(ev.z - m2.z) : 0.f;
    w4.w = valid ? __expf(ev.w - m2.w) : 0.f;
    lsrc[wv][lane] = src;
    *(float4*)&lw[wv][lane * 4] = make_float4(w4.x, w4.y, w4.z, w4.w);
    float4 ss = w4;
#pragma unroll
    for (int o = 1; o < 64; o <<= 1) {
      ss.x += __shfl_xor(ss.x, o);
      ss.y += __shfl_xor(ss.y, o);
      ss.z += __shfl_xor(ss.z, o);
      ss.w += __shfl_xor(ss.w, o);
    }
    s.x = s.x * sc.x + ss.x; s.y = s.y * sc.y + ss.y;
    s.z = s.z * sc.z + ss.z; s.w = s.w * sc.w + ss.w;
    m = m2;
    const int cd = min(64, deg - c0);
    for (int j = 0; j < cd; j += 4) {
      const int s0 = lsrc[wv][j + 0], s1 = lsrc[wv][j + 1];
      const int s2 = lsrc[wv][j + 2], s3 = lsrc[wv][j + 3];
      const float w0 = lw[wv][(j + 0) * 4 + h];
      const float w1 = lw[wv][(j + 1) * 4 + h];
      const float w2 = lw[wv][(j + 2) * 4 + h];
      const float w3 = lw[wv][(j + 3) * 4 + h];
      const ushort4 u0 = *(const ushort4*)(xw + (size_t)s0 * 256 + ch);
      const ushort4 u1 = *(const ushort4*)(xw + (size_t)s1 * 256 + ch);
      const ushort4 u2 = *(const ushort4*)(xw + (size_t)s2 * 256 + ch);
      const ushort4 u3 = *(const ushort4*)(xw + (size_t)s3 * 256 + ch);
      acc.x += w0 * bf2f(u0.x) + w1 * bf2f(u1.x) + w2 * bf2f(u2.x) + w3 * bf2f(u3.x);
      acc.y += w0 * bf2f(u0.y) + w1 * bf2f(u1.y) + w2 * bf2f(u2.y) + w3 * bf2f(u3.y);
      acc.z += w0 * bf2f(u0.z) + w1 * bf2f(u1.z) + w2 * bf2f(u2.z) + w3 * bf2f(u3.z);
      acc.w += w0 * bf2f(u0.w) + w1 * bf2f(u1.w) + w2 * bf2f(u2.w) + w3 * bf2f(u3.w);
    }
  }

  const float sh = (h == 0) ? s.x : (h == 1) ? s.y : (h == 2) ? s.z : s.w;
  const float inv = 1.f / (sh + 1e-16f);
  const float4 b4 = *(const float4*)(bias + ch);
  float o0 = acc.x * inv + b4.x, o1 = acc.y * inv + b4.y;
  float o2 = acc.z * inv + b4.z, o3 = acc.w * inv + b4.w;
  if (applyElu) {
    o0 = o0 > 0.f ? o0 : __expf(o0) - 1.f;
    o1 = o1 > 0.f ? o1 : __expf(o1) - 1.f;
    o2 = o2 > 0.f ? o2 : __expf(o2) - 1.f;
    o3 = o3 > 0.f ? o3 : __expf(o3) - 1.f;
  }
  ushort4 o4;
  o4.x = f2bf(o0); o4.y = f2bf(o1); o4.z = f2bf(o2); o4.w = f2bf(o3);
  *(ushort4*)(hout + (size_t)n * 256 + ch) = o4;
}

__global__ __launch_bounds__(256) void aggregate40_lsm_kernel(
    const ushort* __restrict__ xw, const float* __restrict__ asB, const float* __restrict__ adB,
    const int* __restrict__ rowPtr, const int* __restrict__ colSrc,
    const float* __restrict__ bias, float* __restrict__ out) {
  __shared__ int   lsrc[4][64];
  __shared__ float lw[4][64];
  const int n = (blockIdx.x * blockDim.x + threadIdx.x) >> 6;
  if (n >= NN) return;
  const int lane = threadIdx.x & 63;
  const int wv = (threadIdx.x >> 6) & 3;
  const bool act = lane < 40;
  const int p0 = rowPtr[n], deg = rowPtr[n + 1] - p0;
  const float adn = adB[n];
  float m = leaky(asB[n] + adn);
  float s = 1.f;
  float acc = act ? bf2f(xw[(size_t)n * 40 + lane]) : 0.f;

  for (int c0 = 0; c0 < deg; c0 += 64) {
    const int e = c0 + lane;
    const bool valid = e < deg;
    const int src = valid ? colSrc[p0 + e] : n;
    const float a = asB[src];
    float ev = valid ? leaky(a + adn) : -3.0e38f;
    float mc = ev;
#pragma unroll
    for (int o = 1; o < 64; o <<= 1) mc = fmaxf(mc, __shfl_xor(mc, o));
    const float m2 = fmaxf(m, mc);
    const float scl = __expf(m - m2);
    acc *= scl;
    float wv_ = valid ? __expf(ev - m2) : 0.f;
    lsrc[wv][lane] = src;
    lw[wv][lane] = wv_;
    float ss = wv_;
#pragma unroll
    for (int o = 1; o < 64; o <<= 1) ss += __shfl_xor(ss, o);
    s = s * scl + ss;
    m = m2;
    const int cd = min(64, deg - c0);
    for (int j = 0; j < cd; j += 4) {
      const int s0 = lsrc[wv][j + 0], s1 = lsrc[wv][j + 1];
      const int s2 = lsrc[wv][j + 2], s3 = lsrc[wv][j + 3];
      const float w0 = lw[wv][j + 0], w1 = lw[wv][j + 1];
      const float w2 = lw[wv][j + 2], w3 = lw[wv][j + 3];
      const float x0 = act ? bf2f(xw[(size_t)s0 * 40 + lane]) : 0.f;
      const float x1 = act ? bf2f(xw[(size_t)s1 * 40 + lane]) : 0.f;
      const float x2 = act ? bf2f(xw[(size_t)s2 * 40 + lane]) : 0.f;
      const float x3 = act ? bf2f(xw[(size_t)s3 * 40 + lane]) : 0.f;
      acc += w0 * x0 + w1 * x1 + w2 * x2 + w3 * x3;
    }
  }

  float val = acc / (s + 1e-16f) + (act ? bias[lane] : 0.f);
  float v = act ? val : -1e30f;
  float mx = v;
#pragma unroll
  for (int o = 1; o < 64; o <<= 1) mx = fmaxf(mx, __shfl_xor(mx, o));
  float ex = act ? __expf(val - mx) : 0.f;
#pragma unroll
  for (int o = 1; o < 64; o <<= 1) ex += __shfl_xor(ex, o);
  if (act) out[(size_t)n * 40 + lane] = val - mx - __logf(ex);
}

// ---------------- launch ----------------

extern "C" void kernel_launch(void* const* d_in, const int* in_sizes, int n_in,
                              void* d_out, int out_size, void* d_ws, size_t ws_size,
                              hipStream_t stream) {
  const float* x   = (const float*)d_in[0];
  const int*   ei  = (const int*)d_in[1];
  const float* W1  = (const float*)d_in[2];
  const float* a1s = (const float*)d_in[3];
  const float* a1d = (const float*)d_in[4];
  const float* b1  = (const float*)d_in[5];
  const float* W2  = (const float*)d_in[6];
  const float* a2s = (const float*)d_in[7];
  const float* a2d = (const float*)d_in[8];
  const float* b2  = (const float*)d_in[9];
  const float* W3  = (const float*)d_in[10];
  const float* a3s = (const float*)d_in[11];
  const float* a3d = (const float*)d_in[12];
  const float* b3  = (const float*)d_in[13];
  float* out = (float*)d_out;

  char* w = (char*)d_ws;
  ushort* xwBuf = (ushort*)w;  w += (size_t)NN * 256 * 2;
  ushort* hBuf  = (ushort*)w;  w += (size_t)NN * 256 * 2;
  ushort* xw40  = (ushort*)w;  w += (size_t)NN * 40 * 2;
  float* asBuf  = (float*)w;   w += (size_t)NN * 4 * 4;
  float* adBuf  = (float*)w;   w += (size_t)NN * 4 * 4;
  ushort* Bf1   = (ushort*)w;  w += (size_t)17 * 4 * 512 * 2;
  ushort* Bf2   = (ushort*)w;  w += (size_t)17 * 8 * 512 * 2;
  ushort* Bf3   = (ushort*)w;  w += (size_t)3 * 8 * 512 * 2;
  int* counts   = (int*)w;     w += (size_t)NN * 4;
  int* cursor   = (int*)w;     w += (size_t)NN * 4;
  int* rowPtr   = (int*)w;     w += (size_t)(NN + 1) * 4;
  int* colSrc   = (int*)w;     w += (size_t)NE * 4;
  int* partial  = (int*)w;     w += (size_t)NN * 4;
  int* blockSums = (int*)w;    w += 64 * 4;

  const int nScanBlocks = (NN + 1023) / 1024;

  // CSR build
  hipMemsetAsync(counts, 0, (size_t)2 * NN * 4, stream);
  hist_kernel<<<(NE + 255) / 256, 256, 0, stream>>>(ei + NE, counts);
  scan1_kernel<<<nScanBlocks, 1024, 0, stream>>>(counts, partial, blockSums);
  scan2_kernel<<<1, 64, 0, stream>>>(blockSums, nScanBlocks);
  scan3_kernel<<<(NN + 255) / 256, 256, 0, stream>>>(partial, blockSums, rowPtr);
  fill_kernel<<<(NE + 255) / 256, 256, 0, stream>>>(ei, ei + NE, rowPtr, cursor, colSrc);

  // pre-fragment weights (+ fused logit columns)
  prefrag_kernel<<<(17 * 4 * 512 + 255) / 256, 256, 0, stream>>>(W1, a1s, a1d, Bf1, 128, 256, 4, 64, 17);
  prefrag_kernel<<<(17 * 8 * 512 + 255) / 256, 256, 0, stream>>>(W2, a2s, a2d, Bf2, 256, 256, 4, 64, 17);
  prefrag_kernel<<<(3 * 8 * 512 + 255) / 256, 256, 0, stream>>>(W3, a3s, a3d, Bf3, 256, 40, 1, 40, 3);

  const int gemmBlocks = (NN + 63) / 64;  // 782
  const int nodeBlocks = NN / 4;

  // layer 1: 128 -> 4x64 (fp32 A converted on the fly)
  gemm_mfma_kernel<17, 4, true><<<gemmBlocks, 256, 0, stream>>>(x, Bf1, xwBuf, asBuf, adBuf, 256, 4);
  aggregate256_kernel<<<nodeBlocks, 256, 0, stream>>>(xwBuf, asBuf, adBuf, rowPtr, colSrc, b1, hBuf, 1);

  // layer 2: 256 -> 4x64
  gemm_mfma_kernel<17, 8, false><<<gemmBlocks, 256, 0, stream>>>(hBuf, Bf2, xwBuf, asBuf, adBuf, 256, 4);
  aggregate256_kernel<<<nodeBlocks, 256, 0, stream>>>(xwBuf, asBuf, adBuf, rowPtr, colSrc, b2, hBuf, 1);

  // layer 3: 256 -> 40 (+ log_softmax)
  gemm_mfma_kernel<3, 8, false><<<gemmBlocks, 256, 0, stream>>>(hBuf, Bf3, xw40, asBuf, adBuf, 40, 1);
  aggregate40_lsm_kernel<<<nodeBlocks, 256, 0, stream>>>(xw40, asBuf, adBuf, rowPtr, colSrc, b3, out);
}

// Round 7
// 419.919 us; speedup vs baseline: 1.7688x; 1.1244x over previous
//
#include <hip/hip_runtime.h>
#include <hip/hip_bf16.h>

#define NN 50000
#define NE 800000

using bf16x8 = __attribute__((ext_vector_type(8))) short;
using f32x4  = __attribute__((ext_vector_type(4))) float;

__device__ __forceinline__ ushort f2bf(float f) {
  uint x = __float_as_uint(f);
  return (ushort)((x + 0x7FFFu + ((x >> 16) & 1u)) >> 16);
}
__device__ __forceinline__ float bf2f(ushort u) {
  return __uint_as_float(((uint)u) << 16);
}
__device__ __forceinline__ float leaky(float x) { return fmaxf(x, 0.2f * x); }

// async global->LDS, 16B per lane; LDS dest is wave-uniform base + lane*16
__device__ __forceinline__ void gload_lds16(const void* g, void* l) {
  __builtin_amdgcn_global_load_lds(
      (const __attribute__((address_space(1))) unsigned int*)g,
      (__attribute__((address_space(3))) unsigned int*)l, 16, 0, 0);
}

// ---------------- CSR build ----------------

__global__ __launch_bounds__(256) void hist_kernel(const int* __restrict__ dst,
                                                   int* __restrict__ counts) {
  int e = blockIdx.x * 256 + threadIdx.x;
  if (e < NE) atomicAdd(&counts[dst[e]], 1);
}

__global__ __launch_bounds__(1024) void scan1_kernel(const int* __restrict__ counts,
                                                     int* __restrict__ partial,
                                                     int* __restrict__ blockSums) {
  __shared__ int sm[1024];
  int i = blockIdx.x * 1024 + threadIdx.x;
  sm[threadIdx.x] = (i < NN) ? counts[i] : 0;
  __syncthreads();
  for (int off = 1; off < 1024; off <<= 1) {
    int t = (threadIdx.x >= off) ? sm[threadIdx.x - off] : 0;
    __syncthreads();
    sm[threadIdx.x] += t;
    __syncthreads();
  }
  if (i < NN) partial[i] = sm[threadIdx.x];
  if (threadIdx.x == 1023) blockSums[blockIdx.x] = sm[1023];
}

// scan3 with inline prefix over blockSums (replaces old scan2+scan3)
__global__ __launch_bounds__(256) void scan23_kernel(const int* __restrict__ partial,
                                                     const int* __restrict__ blockSums,
                                                     int* __restrict__ rowPtr) {
  int i = blockIdx.x * 256 + threadIdx.x;
  if (i < NN) {
    const int nb = i >> 10;
    int off = 0;
    for (int b = 0; b < nb; ++b) off += blockSums[b];
    rowPtr[i + 1] = partial[i] + off;
    if (i == 0) rowPtr[0] = 0;
  }
}

__global__ __launch_bounds__(256) void fill_kernel(const int* __restrict__ srcArr,
                                                   const int* __restrict__ dstArr,
                                                   const int* __restrict__ rowPtr,
                                                   int* __restrict__ cursor,
                                                   int* __restrict__ colSrc) {
  int e = blockIdx.x * 256 + threadIdx.x;
  if (e < NE) {
    int d = dstArr[e];
    int p = rowPtr[d] + atomicAdd(&cursor[d], 1);
    colSrc[p] = srcArr[e];
  }
}

// ---------------- pre-fragment B' = [W | pad | W@att_s | W@att_d | pad] into MFMA lane order ----
// Bf[(ct*KC + kc)*512 + lane*8 + i] = B'[kc*32 + (lane>>4)*8 + i][ct*16 + (lane&15)]

__device__ __forceinline__ void prefrag_one(int idx, const float* __restrict__ W,
                                            const float* __restrict__ atS,
                                            const float* __restrict__ atD,
                                            ushort* __restrict__ Bf,
                                            int Mout, int Mpad, int nh, int Cdim, int KC) {
  const int i = idx & 7;
  const int lane = (idx >> 3) & 63;
  const int kc = (idx >> 9) % KC;
  const int ct = idx / (KC * 512);
  const int k = kc * 32 + (lane >> 4) * 8 + i;
  const int col = ct * 16 + (lane & 15);
  float v = 0.f;
  if (col < Mout) {
    v = W[(size_t)k * Mout + col];
  } else if (col >= Mpad && col < Mpad + nh) {
    const int h = col - Mpad; float s = 0.f;
    for (int c = 0; c < Cdim; ++c) s += W[(size_t)k * Mout + h * Cdim + c] * atS[h * Cdim + c];
    v = s;
  } else if (col >= Mpad + nh && col < Mpad + 2 * nh) {
    const int h = col - Mpad - nh; float s = 0.f;
    for (int c = 0; c < Cdim; ++c) s += W[(size_t)k * Mout + h * Cdim + c] * atD[h * Cdim + c];
    v = s;
  }
  Bf[idx] = f2bf(v);
}

#define T1 (17 * 4 * 512)
#define T2 (17 * 8 * 512)
#define T3 (5 * 8 * 512)

__global__ __launch_bounds__(256) void prefrag_all_kernel(
    const float* __restrict__ W1, const float* __restrict__ a1s, const float* __restrict__ a1d,
    const float* __restrict__ W2, const float* __restrict__ a2s, const float* __restrict__ a2d,
    const float* __restrict__ W3, const float* __restrict__ a3s, const float* __restrict__ a3d,
    ushort* __restrict__ Bf1, ushort* __restrict__ Bf2, ushort* __restrict__ Bf3) {
  int idx = blockIdx.x * 256 + threadIdx.x;
  if (idx < T1) {
    prefrag_one(idx, W1, a1s, a1d, Bf1, 256, 256, 4, 64, 4);
  } else if (idx < T1 + T2) {
    prefrag_one(idx - T1, W2, a2s, a2d, Bf2, 256, 256, 4, 64, 8);
  } else if (idx < T1 + T2 + T3) {
    prefrag_one(idx - T1 - T2, W3, a3s, a3d, Bf3, 40, 64, 1, 40, 8);
  }
}

// ---------------- bf16 MFMA GEMM: LDS-staged B (double-buffered global_load_lds) ----------------

template <int NCT, int KC, bool AF32>
__global__ __launch_bounds__(256) void gemm_mfma_kernel(const void* __restrict__ Araw,
                                                        const ushort* __restrict__ Bf,
                                                        ushort* __restrict__ xw,
                                                        float* __restrict__ asB,
                                                        float* __restrict__ adB,
                                                        int Mpad, int nh) {
  __shared__ __align__(16) ushort sB[2][NCT * 512];
  constexpr int K = KC * 32;
  const int lane = threadIdx.x & 63;
  const int w = threadIdx.x >> 6;
  const int rowBase = blockIdx.x * 64 + w * 16;
  const int arow = min(rowBase + (lane & 15), NN - 1);   // clamp; no early return (barriers!)
  const int koff = (lane >> 4) * 8;
  f32x4 acc[NCT];
#pragma unroll
  for (int ct = 0; ct < NCT; ++ct) acc[ct] = (f32x4){0.f, 0.f, 0.f, 0.f};

#pragma unroll
  for (int ct0 = 0; ct0 < NCT; ++ct0) {
    if ((ct0 & 3) == w)
      gload_lds16(Bf + (((size_t)ct0 * KC) << 9) + lane * 8, &sB[0][ct0 * 512]);
  }
  __syncthreads();

#pragma unroll
  for (int kc = 0; kc < KC; ++kc) {
    const int nb = kc & 1;
    if (kc + 1 < KC) {
#pragma unroll
      for (int ct0 = 0; ct0 < NCT; ++ct0) {
        if ((ct0 & 3) == w)
          gload_lds16(Bf + (((size_t)ct0 * KC + kc + 1) << 9) + lane * 8,
                      &sB[nb ^ 1][ct0 * 512]);
      }
    }
    bf16x8 af;
    if constexpr (AF32) {
      const float* ap = (const float*)Araw + (size_t)arow * K + koff + kc * 32;
      float4 p0 = *(const float4*)ap;
      float4 p1 = *(const float4*)(ap + 4);
      af[0] = (short)f2bf(p0.x); af[1] = (short)f2bf(p0.y);
      af[2] = (short)f2bf(p0.z); af[3] = (short)f2bf(p0.w);
      af[4] = (short)f2bf(p1.x); af[5] = (short)f2bf(p1.y);
      af[6] = (short)f2bf(p1.z); af[7] = (short)f2bf(p1.w);
    } else {
      const ushort* ap = (const ushort*)Araw + (size_t)arow * K + koff + kc * 32;
      af = *reinterpret_cast<const bf16x8*>(ap);
    }
#pragma unroll
    for (int ct = 0; ct < NCT; ++ct) {
      bf16x8 bfr = *reinterpret_cast<const bf16x8*>(&sB[nb][ct * 512 + lane * 8]);
      acc[ct] = __builtin_amdgcn_mfma_f32_16x16x32_bf16(af, bfr, acc[ct], 0, 0, 0);
    }
    __syncthreads();   // drains vmcnt (prefetch DMA) + orders buffer reuse
  }

  const int colL = lane & 15;
  const int rquad = (lane >> 4) * 4;
#pragma unroll
  for (int ct = 0; ct < NCT; ++ct) {
    const int col = ct * 16 + colL;
#pragma unroll
    for (int r = 0; r < 4; ++r) {
      const int row = rowBase + rquad + r;
      if (row < NN) {
        const float v = acc[ct][r];
        if (col < Mpad) {
          xw[(size_t)row * Mpad + col] = f2bf(v);
        } else if (col < Mpad + nh) {
          asB[(size_t)row * nh + (col - Mpad)] = v;
        } else if (col < Mpad + 2 * nh) {
          adB[(size_t)row * nh + (col - Mpad - nh)] = v;
        }
      }
    }
  }
}

// ---------------- aggregation: wave/node, lane-per-edge softmax + unroll-8 weighted gather ------

__global__ __launch_bounds__(256) void aggregate256_kernel(
    const ushort* __restrict__ xw, const float* __restrict__ asB, const float* __restrict__ adB,
    const int* __restrict__ rowPtr, const int* __restrict__ colSrc,
    const float* __restrict__ bias, ushort* __restrict__ hout, int applyElu) {
  __shared__ int   lsrc[4][64];
  __shared__ float lw[4][256];
  const int n = (blockIdx.x * blockDim.x + threadIdx.x) >> 6;
  if (n >= NN) return;
  const int lane = threadIdx.x & 63;
  const int wv = (threadIdx.x >> 6) & 3;
  const int h = lane >> 4;
  const int ch = lane * 4;
  const int p0 = rowPtr[n], deg = rowPtr[n + 1] - p0;
  const float4 ad4 = *(const float4*)(adB + n * 4);
  const float4 as4 = *(const float4*)(asB + n * 4);
  float4 m;
  m.x = leaky(as4.x + ad4.x); m.y = leaky(as4.y + ad4.y);
  m.z = leaky(as4.z + ad4.z); m.w = leaky(as4.w + ad4.w);
  float4 s = make_float4(1.f, 1.f, 1.f, 1.f);
  ushort4 xv4 = *(const ushort4*)(xw + (size_t)n * 256 + ch);
  float4 acc = make_float4(bf2f(xv4.x), bf2f(xv4.y), bf2f(xv4.z), bf2f(xv4.w));

  for (int c0 = 0; c0 < deg; c0 += 64) {
    const int e = c0 + lane;
    const bool valid = e < deg;
    const int src = valid ? colSrc[p0 + e] : n;
    const float4 a4 = *(const float4*)(asB + src * 4);
    float4 ev;
    ev.x = valid ? leaky(a4.x + ad4.x) : -3.0e38f;
    ev.y = valid ? leaky(a4.y + ad4.y) : -3.0e38f;
    ev.z = valid ? leaky(a4.z + ad4.z) : -3.0e38f;
    ev.w = valid ? leaky(a4.w + ad4.w) : -3.0e38f;
    float4 mc = ev;
#pragma unroll
    for (int o = 1; o < 64; o <<= 1) {
      mc.x = fmaxf(mc.x, __shfl_xor(mc.x, o));
      mc.y = fmaxf(mc.y, __shfl_xor(mc.y, o));
      mc.z = fmaxf(mc.z, __shfl_xor(mc.z, o));
      mc.w = fmaxf(mc.w, __shfl_xor(mc.w, o));
    }
    float4 m2;
    m2.x = fmaxf(m.x, mc.x); m2.y = fmaxf(m.y, mc.y);
    m2.z = fmaxf(m.z, mc.z); m2.w = fmaxf(m.w, mc.w);
    float4 sc;
    sc.x = __expf(m.x - m2.x); sc.y = __expf(m.y - m2.y);
    sc.z = __expf(m.z - m2.z); sc.w = __expf(m.w - m2.w);
    const float msc = (h == 0) ? sc.x : (h == 1) ? sc.y : (h == 2) ? sc.z : sc.w;
    acc.x *= msc; acc.y *= msc; acc.z *= msc; acc.w *= msc;
    float4 w4;
    w4.x = valid ? __expf(ev.x - m2.x) : 0.f;
    w4.y = valid ? __expf(ev.y - m2.y) : 0.f;
    w4.z = valid ? __expf(ev.z - m2.z) : 0.f;
    w4.w = valid ? __expf(ev.w - m2.w) : 0.f;
    lsrc[wv][lane] = src;
    *(float4*)&lw[wv][lane * 4] = make_float4(w4.x, w4.y, w4.z, w4.w);
    float4 ss = w4;
#pragma unroll
    for (int o = 1; o < 64; o <<= 1) {
      ss.x += __shfl_xor(ss.x, o);
      ss.y += __shfl_xor(ss.y, o);
      ss.z += __shfl_xor(ss.z, o);
      ss.w += __shfl_xor(ss.w, o);
    }
    s.x = s.x * sc.x + ss.x; s.y = s.y * sc.y + ss.y;
    s.z = s.z * sc.z + ss.z; s.w = s.w * sc.w + ss.w;
    m = m2;
    // ---- weighted gather, 8 rows in flight (tail entries have w=0, src=n) ----
    const int cd = min(64, deg - c0);
    const int cdr = (cd + 7) & ~7;
    for (int j = 0; j < cdr; j += 8) {
      int ssrc[8]; float wj[8];
#pragma unroll
      for (int q = 0; q < 8; ++q) {
        ssrc[q] = lsrc[wv][j + q];
        wj[q] = lw[wv][(j + q) * 4 + h];
      }
      ushort4 u[8];
#pragma unroll
      for (int q = 0; q < 8; ++q)
        u[q] = *(const ushort4*)(xw + (size_t)ssrc[q] * 256 + ch);
#pragma unroll
      for (int q = 0; q < 8; ++q) {
        acc.x += wj[q] * bf2f(u[q].x);
        acc.y += wj[q] * bf2f(u[q].y);
        acc.z += wj[q] * bf2f(u[q].z);
        acc.w += wj[q] * bf2f(u[q].w);
      }
    }
  }

  const float sh = (h == 0) ? s.x : (h == 1) ? s.y : (h == 2) ? s.z : s.w;
  const float inv = 1.f / (sh + 1e-16f);
  const float4 b4 = *(const float4*)(bias + ch);
  float o0 = acc.x * inv + b4.x, o1 = acc.y * inv + b4.y;
  float o2 = acc.z * inv + b4.z, o3 = acc.w * inv + b4.w;
  if (applyElu) {
    o0 = o0 > 0.f ? o0 : __expf(o0) - 1.f;
    o1 = o1 > 0.f ? o1 : __expf(o1) - 1.f;
    o2 = o2 > 0.f ? o2 : __expf(o2) - 1.f;
    o3 = o3 > 0.f ? o3 : __expf(o3) - 1.f;
  }
  ushort4 o4;
  o4.x = f2bf(o0); o4.y = f2bf(o1); o4.z = f2bf(o2); o4.w = f2bf(o3);
  *(ushort4*)(hout + (size_t)n * 256 + ch) = o4;
}

// xw40 padded to 64 cols (bf16): one aligned 128B segment per row, lane reads 1 channel.

__global__ __launch_bounds__(256) void aggregate40_lsm_kernel(
    const ushort* __restrict__ xw, const float* __restrict__ asB, const float* __restrict__ adB,
    const int* __restrict__ rowPtr, const int* __restrict__ colSrc,
    const float* __restrict__ bias, float* __restrict__ out) {
  __shared__ int   lsrc[4][64];
  __shared__ float lw[4][64];
  const int n = (blockIdx.x * blockDim.x + threadIdx.x) >> 6;
  if (n >= NN) return;
  const int lane = threadIdx.x & 63;
  const int wv = (threadIdx.x >> 6) & 3;
  const bool act = lane < 40;
  const int p0 = rowPtr[n], deg = rowPtr[n + 1] - p0;
  const float adn = adB[n];
  float m = leaky(asB[n] + adn);
  float s = 1.f;
  float acc = bf2f(xw[(size_t)n * 64 + lane]);   // pad cols are zero

  for (int c0 = 0; c0 < deg; c0 += 64) {
    const int e = c0 + lane;
    const bool valid = e < deg;
    const int src = valid ? colSrc[p0 + e] : n;
    const float a = asB[src];
    float ev = valid ? leaky(a + adn) : -3.0e38f;
    float mc = ev;
#pragma unroll
    for (int o = 1; o < 64; o <<= 1) mc = fmaxf(mc, __shfl_xor(mc, o));
    const float m2 = fmaxf(m, mc);
    const float scl = __expf(m - m2);
    acc *= scl;
    float wv_ = valid ? __expf(ev - m2) : 0.f;
    lsrc[wv][lane] = src;
    lw[wv][lane] = wv_;
    float ss = wv_;
#pragma unroll
    for (int o = 1; o < 64; o <<= 1) ss += __shfl_xor(ss, o);
    s = s * scl + ss;
    m = m2;
    const int cd = min(64, deg - c0);
    const int cdr = (cd + 7) & ~7;
    for (int j = 0; j < cdr; j += 8) {
      int ssrc[8]; float wj[8];
#pragma unroll
      for (int q = 0; q < 8; ++q) { ssrc[q] = lsrc[wv][j + q]; wj[q] = lw[wv][j + q]; }
      ushort u[8];
#pragma unroll
      for (int q = 0; q < 8; ++q) u[q] = xw[(size_t)ssrc[q] * 64 + lane];
#pragma unroll
      for (int q = 0; q < 8; ++q) acc += wj[q] * bf2f(u[q]);
    }
  }

  float val = acc / (s + 1e-16f) + (act ? bias[lane] : 0.f);
  float v = act ? val : -1e30f;
  float mx = v;
#pragma unroll
  for (int o = 1; o < 64; o <<= 1) mx = fmaxf(mx, __shfl_xor(mx, o));
  float ex = act ? __expf(val - mx) : 0.f;
#pragma unroll
  for (int o = 1; o < 64; o <<= 1) ex += __shfl_xor(ex, o);
  if (act) out[(size_t)n * 40 + lane] = val - mx - __logf(ex);
}

// ---------------- launch ----------------

extern "C" void kernel_launch(void* const* d_in, const int* in_sizes, int n_in,
                              void* d_out, int out_size, void* d_ws, size_t ws_size,
                              hipStream_t stream) {
  const float* x   = (const float*)d_in[0];
  const int*   ei  = (const int*)d_in[1];
  const float* W1  = (const float*)d_in[2];
  const float* a1s = (const float*)d_in[3];
  const float* a1d = (const float*)d_in[4];
  const float* b1  = (const float*)d_in[5];
  const float* W2  = (const float*)d_in[6];
  const float* a2s = (const float*)d_in[7];
  const float* a2d = (const float*)d_in[8];
  const float* b2  = (const float*)d_in[9];
  const float* W3  = (const float*)d_in[10];
  const float* a3s = (const float*)d_in[11];
  const float* a3d = (const float*)d_in[12];
  const float* b3  = (const float*)d_in[13];
  float* out = (float*)d_out;

  char* w = (char*)d_ws;
  ushort* xwBuf = (ushort*)w;  w += (size_t)NN * 256 * 2;
  ushort* hBuf  = (ushort*)w;  w += (size_t)NN * 256 * 2;
  ushort* xw40  = (ushort*)w;  w += (size_t)NN * 64 * 2;
  float* asBuf  = (float*)w;   w += (size_t)NN * 4 * 4;
  float* adBuf  = (float*)w;   w += (size_t)NN * 4 * 4;
  ushort* Bf1   = (ushort*)w;  w += (size_t)T1 * 2;
  ushort* Bf2   = (ushort*)w;  w += (size_t)T2 * 2;
  ushort* Bf3   = (ushort*)w;  w += (size_t)T3 * 2;
  int* counts   = (int*)w;     w += (size_t)NN * 4;
  int* cursor   = (int*)w;     w += (size_t)NN * 4;
  int* rowPtr   = (int*)w;     w += (size_t)(NN + 1) * 4;
  int* colSrc   = (int*)w;     w += (size_t)NE * 4;
  int* partial  = (int*)w;     w += (size_t)NN * 4;
  int* blockSums = (int*)w;    w += 64 * 4;

  const int nScanBlocks = (NN + 1023) / 1024;  // 49

  // CSR build
  hipMemsetAsync(counts, 0, (size_t)2 * NN * 4, stream);
  hist_kernel<<<(NE + 255) / 256, 256, 0, stream>>>(ei + NE, counts);
  scan1_kernel<<<nScanBlocks, 1024, 0, stream>>>(counts, partial, blockSums);
  scan23_kernel<<<(NN + 255) / 256, 256, 0, stream>>>(partial, blockSums, rowPtr);
  fill_kernel<<<(NE + 255) / 256, 256, 0, stream>>>(ei, ei + NE, rowPtr, cursor, colSrc);

  // pre-fragment all weights (+ fused logit columns)
  prefrag_all_kernel<<<(T1 + T2 + T3 + 255) / 256, 256, 0, stream>>>(
      W1, a1s, a1d, W2, a2s, a2d, W3, a3s, a3d, Bf1, Bf2, Bf3);

  const int gemmBlocks = (NN + 63) / 64;  // 782
  const int nodeBlocks = NN / 4;

  // layer 1: 128 -> 4x64 (fp32 A converted on the fly)
  gemm_mfma_kernel<17, 4, true><<<gemmBlocks, 256, 0, stream>>>(x, Bf1, xwBuf, asBuf, adBuf, 256, 4);
  aggregate256_kernel<<<nodeBlocks, 256, 0, stream>>>(xwBuf, asBuf, adBuf, rowPtr, colSrc, b1, hBuf, 1);

  // layer 2: 256 -> 4x64
  gemm_mfma_kernel<17, 8, false><<<gemmBlocks, 256, 0, stream>>>(hBuf, Bf2, xwBuf, asBuf, adBuf, 256, 4);
  aggregate256_kernel<<<nodeBlocks, 256, 0, stream>>>(xwBuf, asBuf, adBuf, rowPtr, colSrc, b2, hBuf, 1);

  // layer 3: 256 -> 40 (padded to 64) + log_softmax
  gemm_mfma_kernel<5, 8, false><<<gemmBlocks, 256, 0, stream>>>(hBuf, Bf3, xw40, asBuf, adBuf, 64, 1);
  aggregate40_lsm_kernel<<<nodeBlocks, 256, 0, stream>>>(xw40, asBuf, adBuf, rowPtr, colSrc, b3, out);
}

// Round 8
// 389.272 us; speedup vs baseline: 1.9081x; 1.0787x over previous
//
#include <hip/hip_runtime.h>
#include <hip/hip_bf16.h>

#define NN 50000
#define NE 800000

using bf16x8 = __attribute__((ext_vector_type(8))) short;
using f32x4  = __attribute__((ext_vector_type(4))) float;
using f32x2  = __attribute__((ext_vector_type(2))) float;

__device__ __forceinline__ ushort f2bf(float f) {
  uint x = __float_as_uint(f);
  return (ushort)((x + 0x7FFFu + ((x >> 16) & 1u)) >> 16);
}
__device__ __forceinline__ float bf2f(ushort u) {
  return __uint_as_float(((uint)u) << 16);
}
__device__ __forceinline__ float leaky(float x) { return fmaxf(x, 0.2f * x); }

// fp8 e4m3 (OCP) helpers — HW packed converts
__device__ __forceinline__ unsigned char f32_to_fp8(float v) {
  int pk = __builtin_amdgcn_cvt_pk_fp8_f32(v, v, 0, false);
  return (unsigned char)(pk & 0xff);
}
__device__ __forceinline__ float4 fp8x4_to_f32(uint u) {
  f32x2 lo = __builtin_amdgcn_cvt_pk_f32_fp8((int)u, false);  // bytes 0,1
  f32x2 hi = __builtin_amdgcn_cvt_pk_f32_fp8((int)u, true);   // bytes 2,3
  return make_float4(lo[0], lo[1], hi[0], hi[1]);
}

// async global->LDS, 16B per lane; LDS dest is wave-uniform base + lane*16
__device__ __forceinline__ void gload_lds16(const void* g, void* l) {
  __builtin_amdgcn_global_load_lds(
      (const __attribute__((address_space(1))) unsigned int*)g,
      (__attribute__((address_space(3))) unsigned int*)l, 16, 0, 0);
}

// ---------------- CSR build ----------------

__global__ __launch_bounds__(256) void hist_kernel(const int* __restrict__ dst,
                                                   int* __restrict__ counts) {
  int e = blockIdx.x * 256 + threadIdx.x;
  if (e < NE) atomicAdd(&counts[dst[e]], 1);
}

__global__ __launch_bounds__(1024) void scan1_kernel(const int* __restrict__ counts,
                                                     int* __restrict__ partial,
                                                     int* __restrict__ blockSums) {
  __shared__ int sm[1024];
  int i = blockIdx.x * 1024 + threadIdx.x;
  sm[threadIdx.x] = (i < NN) ? counts[i] : 0;
  __syncthreads();
  for (int off = 1; off < 1024; off <<= 1) {
    int t = (threadIdx.x >= off) ? sm[threadIdx.x - off] : 0;
    __syncthreads();
    sm[threadIdx.x] += t;
    __syncthreads();
  }
  if (i < NN) partial[i] = sm[threadIdx.x];
  if (threadIdx.x == 1023) blockSums[blockIdx.x] = sm[1023];
}

__global__ __launch_bounds__(256) void scan23_kernel(const int* __restrict__ partial,
                                                     const int* __restrict__ blockSums,
                                                     int* __restrict__ rowPtr) {
  int i = blockIdx.x * 256 + threadIdx.x;
  if (i < NN) {
    const int nb = i >> 10;
    int off = 0;
    for (int b = 0; b < nb; ++b) off += blockSums[b];
    rowPtr[i + 1] = partial[i] + off;
    if (i == 0) rowPtr[0] = 0;
  }
}

__global__ __launch_bounds__(256) void fill_kernel(const int* __restrict__ srcArr,
                                                   const int* __restrict__ dstArr,
                                                   const int* __restrict__ rowPtr,
                                                   int* __restrict__ cursor,
                                                   int* __restrict__ colSrc) {
  int e = blockIdx.x * 256 + threadIdx.x;
  if (e < NE) {
    int d = dstArr[e];
    int p = rowPtr[d] + atomicAdd(&cursor[d], 1);
    colSrc[p] = srcArr[e];
  }
}

// ---------------- pre-fragment B' = [W | pad | W@att_s | W@att_d | pad] into MFMA lane order ----

__device__ __forceinline__ void prefrag_one(int idx, const float* __restrict__ W,
                                            const float* __restrict__ atS,
                                            const float* __restrict__ atD,
                                            ushort* __restrict__ Bf,
                                            int Mout, int Mpad, int nh, int Cdim, int KC) {
  const int i = idx & 7;
  const int lane = (idx >> 3) & 63;
  const int kc = (idx >> 9) % KC;
  const int ct = idx / (KC * 512);
  const int k = kc * 32 + (lane >> 4) * 8 + i;
  const int col = ct * 16 + (lane & 15);
  float v = 0.f;
  if (col < Mout) {
    v = W[(size_t)k * Mout + col];
  } else if (col >= Mpad && col < Mpad + nh) {
    const int h = col - Mpad; float s = 0.f;
    for (int c = 0; c < Cdim; ++c) s += W[(size_t)k * Mout + h * Cdim + c] * atS[h * Cdim + c];
    v = s;
  } else if (col >= Mpad + nh && col < Mpad + 2 * nh) {
    const int h = col - Mpad - nh; float s = 0.f;
    for (int c = 0; c < Cdim; ++c) s += W[(size_t)k * Mout + h * Cdim + c] * atD[h * Cdim + c];
    v = s;
  }
  Bf[idx] = f2bf(v);
}

#define T1 (17 * 4 * 512)
#define T2 (17 * 8 * 512)
#define T3 (5 * 8 * 512)

__global__ __launch_bounds__(256) void prefrag_all_kernel(
    const float* __restrict__ W1, const float* __restrict__ a1s, const float* __restrict__ a1d,
    const float* __restrict__ W2, const float* __restrict__ a2s, const float* __restrict__ a2d,
    const float* __restrict__ W3, const float* __restrict__ a3s, const float* __restrict__ a3d,
    ushort* __restrict__ Bf1, ushort* __restrict__ Bf2, ushort* __restrict__ Bf3) {
  int idx = blockIdx.x * 256 + threadIdx.x;
  if (idx < T1) {
    prefrag_one(idx, W1, a1s, a1d, Bf1, 256, 256, 4, 64, 4);
  } else if (idx < T1 + T2) {
    prefrag_one(idx - T1, W2, a2s, a2d, Bf2, 256, 256, 4, 64, 8);
  } else if (idx < T1 + T2 + T3) {
    prefrag_one(idx - T1 - T2, W3, a3s, a3d, Bf3, 40, 64, 1, 40, 8);
  }
}

// ---------------- bf16 MFMA GEMM: 128-row blocks (8 waves), LDS-staged double-buffered B ------
// OUT8: write xw as fp8 e4m3 (message payload); else bf16.

template <int NCT, int KC, bool AF32, bool OUT8>
__global__ __launch_bounds__(512) void gemm_mfma_kernel(const void* __restrict__ Araw,
                                                        const ushort* __restrict__ Bf,
                                                        void* __restrict__ xwOut,
                                                        float* __restrict__ asB,
                                                        float* __restrict__ adB,
                                                        int Mpad, int nh) {
  __shared__ __align__(16) ushort sB[2][NCT * 512];
  constexpr int K = KC * 32;
  const int lane = threadIdx.x & 63;
  const int w = threadIdx.x >> 6;         // 8 waves
  const int rowBase = blockIdx.x * 128 + w * 16;
  const int arow = min(rowBase + (lane & 15), NN - 1);   // clamp; no early return (barriers!)
  const int koff = (lane >> 4) * 8;
  f32x4 acc[NCT];
#pragma unroll
  for (int ct = 0; ct < NCT; ++ct) acc[ct] = (f32x4){0.f, 0.f, 0.f, 0.f};

#pragma unroll
  for (int ct0 = 0; ct0 < NCT; ++ct0) {
    if ((ct0 & 7) == w)
      gload_lds16(Bf + (((size_t)ct0 * KC) << 9) + lane * 8, &sB[0][ct0 * 512]);
  }
  __syncthreads();

#pragma unroll
  for (int kc = 0; kc < KC; ++kc) {
    const int nb = kc & 1;
    if (kc + 1 < KC) {
#pragma unroll
      for (int ct0 = 0; ct0 < NCT; ++ct0) {
        if ((ct0 & 7) == w)
          gload_lds16(Bf + (((size_t)ct0 * KC + kc + 1) << 9) + lane * 8,
                      &sB[nb ^ 1][ct0 * 512]);
      }
    }
    bf16x8 af;
    if constexpr (AF32) {
      const float* ap = (const float*)Araw + (size_t)arow * K + koff + kc * 32;
      float4 p0 = *(const float4*)ap;
      float4 p1 = *(const float4*)(ap + 4);
      af[0] = (short)f2bf(p0.x); af[1] = (short)f2bf(p0.y);
      af[2] = (short)f2bf(p0.z); af[3] = (short)f2bf(p0.w);
      af[4] = (short)f2bf(p1.x); af[5] = (short)f2bf(p1.y);
      af[6] = (short)f2bf(p1.z); af[7] = (short)f2bf(p1.w);
    } else {
      const ushort* ap = (const ushort*)Araw + (size_t)arow * K + koff + kc * 32;
      af = *reinterpret_cast<const bf16x8*>(ap);
    }
#pragma unroll
    for (int ct = 0; ct < NCT; ++ct) {
      bf16x8 bfr = *reinterpret_cast<const bf16x8*>(&sB[nb][ct * 512 + lane * 8]);
      acc[ct] = __builtin_amdgcn_mfma_f32_16x16x32_bf16(af, bfr, acc[ct], 0, 0, 0);
    }
    __syncthreads();   // drains vmcnt (prefetch DMA) + orders buffer reuse
  }

  const int colL = lane & 15;
  const int rquad = (lane >> 4) * 4;
#pragma unroll
  for (int ct = 0; ct < NCT; ++ct) {
    const int col = ct * 16 + colL;
#pragma unroll
    for (int r = 0; r < 4; ++r) {
      const int row = rowBase + rquad + r;
      if (row < NN) {
        const float v = acc[ct][r];
        if (col < Mpad) {
          if constexpr (OUT8) {
            ((unsigned char*)xwOut)[(size_t)row * Mpad + col] = f32_to_fp8(v);
          } else {
            ((ushort*)xwOut)[(size_t)row * Mpad + col] = f2bf(v);
          }
        } else if (col < Mpad + nh) {
          asB[(size_t)row * nh + (col - Mpad)] = v;
        } else if (col < Mpad + 2 * nh) {
          adB[(size_t)row * nh + (col - Mpad - nh)] = v;
        }
      }
    }
  }
}

// ---------------- aggregation: wave/node, lane-per-edge softmax + fp8 weighted gather ----------

__global__ __launch_bounds__(256) void aggregate256_kernel(
    const unsigned char* __restrict__ xw, const float* __restrict__ asB,
    const float* __restrict__ adB,
    const int* __restrict__ rowPtr, const int* __restrict__ colSrc,
    const float* __restrict__ bias, ushort* __restrict__ hout, int applyElu) {
  __shared__ int   lsrc[4][64];
  __shared__ float lw[4][256];
  const int n = (blockIdx.x * blockDim.x + threadIdx.x) >> 6;
  if (n >= NN) return;
  const int lane = threadIdx.x & 63;
  const int wv = (threadIdx.x >> 6) & 3;
  const int h = lane >> 4;
  const int ch = lane * 4;                 // channel (and byte) offset in a 256-ch fp8 row
  const int p0 = rowPtr[n], deg = rowPtr[n + 1] - p0;
  const float4 ad4 = *(const float4*)(adB + n * 4);
  const float4 as4 = *(const float4*)(asB + n * 4);
  float4 m;
  m.x = leaky(as4.x + ad4.x); m.y = leaky(as4.y + ad4.y);
  m.z = leaky(as4.z + ad4.z); m.w = leaky(as4.w + ad4.w);
  float4 s = make_float4(1.f, 1.f, 1.f, 1.f);
  float4 acc = fp8x4_to_f32(*(const uint*)(xw + (size_t)n * 256 + ch));  // self message

  for (int c0 = 0; c0 < deg; c0 += 64) {
    const int e = c0 + lane;
    const bool valid = e < deg;
    const int src = valid ? colSrc[p0 + e] : n;
    const float4 a4 = *(const float4*)(asB + src * 4);
    float4 ev;
    ev.x = valid ? leaky(a4.x + ad4.x) : -3.0e38f;
    ev.y = valid ? leaky(a4.y + ad4.y) : -3.0e38f;
    ev.z = valid ? leaky(a4.z + ad4.z) : -3.0e38f;
    ev.w = valid ? leaky(a4.w + ad4.w) : -3.0e38f;
    float4 mc = ev;
#pragma unroll
    for (int o = 1; o < 64; o <<= 1) {
      mc.x = fmaxf(mc.x, __shfl_xor(mc.x, o));
      mc.y = fmaxf(mc.y, __shfl_xor(mc.y, o));
      mc.z = fmaxf(mc.z, __shfl_xor(mc.z, o));
      mc.w = fmaxf(mc.w, __shfl_xor(mc.w, o));
    }
    float4 m2;
    m2.x = fmaxf(m.x, mc.x); m2.y = fmaxf(m.y, mc.y);
    m2.z = fmaxf(m.z, mc.z); m2.w = fmaxf(m.w, mc.w);
    float4 sc;
    sc.x = __expf(m.x - m2.x); sc.y = __expf(m.y - m2.y);
    sc.z = __expf(m.z - m2.z); sc.w = __expf(m.w - m2.w);
    const float msc = (h == 0) ? sc.x : (h == 1) ? sc.y : (h == 2) ? sc.z : sc.w;
    acc.x *= msc; acc.y *= msc; acc.z *= msc; acc.w *= msc;
    float4 w4;
    w4.x = valid ? __expf(ev.x - m2.x) : 0.f;
    w4.y = valid ? __expf(ev.y - m2.y) : 0.f;
    w4.z = valid ? __expf(ev.z - m2.z) : 0.f;
    w4.w = valid ? __expf(ev.w - m2.w) : 0.f;
    lsrc[wv][lane] = src;
    *(float4*)&lw[wv][lane * 4] = make_float4(w4.x, w4.y, w4.z, w4.w);
    float4 ss = w4;
#pragma unroll
    for (int o = 1; o < 64; o <<= 1) {
      ss.x += __shfl_xor(ss.x, o);
      ss.y += __shfl_xor(ss.y, o);
      ss.z += __shfl_xor(ss.z, o);
      ss.w += __shfl_xor(ss.w, o);
    }
    s.x = s.x * sc.x + ss.x; s.y = s.y * sc.y + ss.y;
    s.z = s.z * sc.z + ss.z; s.w = s.w * sc.w + ss.w;
    m = m2;
    // ---- weighted gather, 8 rows in flight (tail entries have w=0, src=n) ----
    const int cd = min(64, deg - c0);
    const int cdr = (cd + 7) & ~7;
    for (int j = 0; j < cdr; j += 8) {
      int ssrc[8]; float wj[8];
#pragma unroll
      for (int q = 0; q < 8; ++q) {
        ssrc[q] = lsrc[wv][j + q];
        wj[q] = lw[wv][(j + q) * 4 + h];
      }
      uint u[8];
#pragma unroll
      for (int q = 0; q < 8; ++q)
        u[q] = *(const uint*)(xw + (size_t)ssrc[q] * 256 + ch);
#pragma unroll
      for (int q = 0; q < 8; ++q) {
        const float4 x4 = fp8x4_to_f32(u[q]);
        acc.x += wj[q] * x4.x;
        acc.y += wj[q] * x4.y;
        acc.z += wj[q] * x4.z;
        acc.w += wj[q] * x4.w;
      }
    }
  }

  const float sh = (h == 0) ? s.x : (h == 1) ? s.y : (h == 2) ? s.z : s.w;
  const float inv = 1.f / (sh + 1e-16f);
  const float4 b4 = *(const float4*)(bias + ch);
  float o0 = acc.x * inv + b4.x, o1 = acc.y * inv + b4.y;
  float o2 = acc.z * inv + b4.z, o3 = acc.w * inv + b4.w;
  if (applyElu) {
    o0 = o0 > 0.f ? o0 : __expf(o0) - 1.f;
    o1 = o1 > 0.f ? o1 : __expf(o1) - 1.f;
    o2 = o2 > 0.f ? o2 : __expf(o2) - 1.f;
    o3 = o3 > 0.f ? o3 : __expf(o3) - 1.f;
  }
  ushort4 o4;
  o4.x = f2bf(o0); o4.y = f2bf(o1); o4.z = f2bf(o2); o4.w = f2bf(o3);
  *(ushort4*)(hout + (size_t)n * 256 + ch) = o4;
}

// xw40 padded to 64 cols (bf16): one aligned 128B segment per row, lane reads 1 channel.

__global__ __launch_bounds__(256) void aggregate40_lsm_kernel(
    const ushort* __restrict__ xw, const float* __restrict__ asB, const float* __restrict__ adB,
    const int* __restrict__ rowPtr, const int* __restrict__ colSrc,
    const float* __restrict__ bias, float* __restrict__ out) {
  __shared__ int   lsrc[4][64];
  __shared__ float lw[4][64];
  const int n = (blockIdx.x * blockDim.x + threadIdx.x) >> 6;
  if (n >= NN) return;
  const int lane = threadIdx.x & 63;
  const int wv = (threadIdx.x >> 6) & 3;
  const bool act = lane < 40;
  const int p0 = rowPtr[n], deg = rowPtr[n + 1] - p0;
  const float adn = adB[n];
  float m = leaky(asB[n] + adn);
  float s = 1.f;
  float acc = bf2f(xw[(size_t)n * 64 + lane]);   // pad cols are zero

  for (int c0 = 0; c0 < deg; c0 += 64) {
    const int e = c0 + lane;
    const bool valid = e < deg;
    const int src = valid ? colSrc[p0 + e] : n;
    const float a = asB[src];
    float ev = valid ? leaky(a + adn) : -3.0e38f;
    float mc = ev;
#pragma unroll
    for (int o = 1; o < 64; o <<= 1) mc = fmaxf(mc, __shfl_xor(mc, o));
    const float m2 = fmaxf(m, mc);
    const float scl = __expf(m - m2);
    acc *= scl;
    float wv_ = valid ? __expf(ev - m2) : 0.f;
    lsrc[wv][lane] = src;
    lw[wv][lane] = wv_;
    float ss = wv_;
#pragma unroll
    for (int o = 1; o < 64; o <<= 1) ss += __shfl_xor(ss, o);
    s = s * scl + ss;
    m = m2;
    const int cd = min(64, deg - c0);
    const int cdr = (cd + 7) & ~7;
    for (int j = 0; j < cdr; j += 8) {
      int ssrc[8]; float wj[8];
#pragma unroll
      for (int q = 0; q < 8; ++q) { ssrc[q] = lsrc[wv][j + q]; wj[q] = lw[wv][j + q]; }
      ushort u[8];
#pragma unroll
      for (int q = 0; q < 8; ++q) u[q] = xw[(size_t)ssrc[q] * 64 + lane];
#pragma unroll
      for (int q = 0; q < 8; ++q) acc += wj[q] * bf2f(u[q]);
    }
  }

  float val = acc / (s + 1e-16f) + (act ? bias[lane] : 0.f);
  float v = act ? val : -1e30f;
  float mx = v;
#pragma unroll
  for (int o = 1; o < 64; o <<= 1) mx = fmaxf(mx, __shfl_xor(mx, o));
  float ex = act ? __expf(val - mx) : 0.f;
#pragma unroll
  for (int o = 1; o < 64; o <<= 1) ex += __shfl_xor(ex, o);
  if (act) out[(size_t)n * 40 + lane] = val - mx - __logf(ex);
}

// ---------------- launch ----------------

extern "C" void kernel_launch(void* const* d_in, const int* in_sizes, int n_in,
                              void* d_out, int out_size, void* d_ws, size_t ws_size,
                              hipStream_t stream) {
  const float* x   = (const float*)d_in[0];
  const int*   ei  = (const int*)d_in[1];
  const float* W1  = (const float*)d_in[2];
  const float* a1s = (const float*)d_in[3];
  const float* a1d = (const float*)d_in[4];
  const float* b1  = (const float*)d_in[5];
  const float* W2  = (const float*)d_in[6];
  const float* a2s = (const float*)d_in[7];
  const float* a2d = (const float*)d_in[8];
  const float* b2  = (const float*)d_in[9];
  const float* W3  = (const float*)d_in[10];
  const float* a3s = (const float*)d_in[11];
  const float* a3d = (const float*)d_in[12];
  const float* b3  = (const float*)d_in[13];
  float* out = (float*)d_out;

  char* w = (char*)d_ws;
  unsigned char* xwBuf = (unsigned char*)w;  w += (size_t)NN * 256;   // fp8 messages
  ushort* hBuf  = (ushort*)w;  w += (size_t)NN * 256 * 2;             // agg out (bf16)
  ushort* xw40  = (ushort*)w;  w += (size_t)NN * 64 * 2;
  float* asBuf  = (float*)w;   w += (size_t)NN * 4 * 4;
  float* adBuf  = (float*)w;   w += (size_t)NN * 4 * 4;
  ushort* Bf1   = (ushort*)w;  w += (size_t)T1 * 2;
  ushort* Bf2   = (ushort*)w;  w += (size_t)T2 * 2;
  ushort* Bf3   = (ushort*)w;  w += (size_t)T3 * 2;
  int* counts   = (int*)w;     w += (size_t)NN * 4;
  int* cursor   = (int*)w;     w += (size_t)NN * 4;
  int* rowPtr   = (int*)w;     w += (size_t)(NN + 1) * 4;
  int* colSrc   = (int*)w;     w += (size_t)NE * 4;
  int* partial  = (int*)w;     w += (size_t)NN * 4;
  int* blockSums = (int*)w;    w += 64 * 4;

  const int nScanBlocks = (NN + 1023) / 1024;  // 49

  // CSR build
  hipMemsetAsync(counts, 0, (size_t)2 * NN * 4, stream);
  hist_kernel<<<(NE + 255) / 256, 256, 0, stream>>>(ei + NE, counts);
  scan1_kernel<<<nScanBlocks, 1024, 0, stream>>>(counts, partial, blockSums);
  scan23_kernel<<<(NN + 255) / 256, 256, 0, stream>>>(partial, blockSums, rowPtr);
  fill_kernel<<<(NE + 255) / 256, 256, 0, stream>>>(ei, ei + NE, rowPtr, cursor, colSrc);

  // pre-fragment all weights (+ fused logit columns)
  prefrag_all_kernel<<<(T1 + T2 + T3 + 255) / 256, 256, 0, stream>>>(
      W1, a1s, a1d, W2, a2s, a2d, W3, a3s, a3d, Bf1, Bf2, Bf3);

  const int gemmBlocks = (NN + 127) / 128;  // 391 (128 rows / block, 8 waves)
  const int nodeBlocks = NN / 4;            // wave per node

  // layer 1: 128 -> 4x64 (fp32 A converted on the fly; fp8 message out)
  gemm_mfma_kernel<17, 4, true, true><<<gemmBlocks, 512, 0, stream>>>(x, Bf1, xwBuf, asBuf, adBuf, 256, 4);
  aggregate256_kernel<<<nodeBlocks, 256, 0, stream>>>(xwBuf, asBuf, adBuf, rowPtr, colSrc, b1, hBuf, 1);

  // layer 2: 256 -> 4x64 (fp8 message out)
  gemm_mfma_kernel<17, 8, false, true><<<gemmBlocks, 512, 0, stream>>>(hBuf, Bf2, xwBuf, asBuf, adBuf, 256, 4);
  aggregate256_kernel<<<nodeBlocks, 256, 0, stream>>>(xwBuf, asBuf, adBuf, rowPtr, colSrc, b2, hBuf, 1);

  // layer 3: 256 -> 40 (padded to 64, bf16) + log_softmax
  gemm_mfma_kernel<5, 8, false, false><<<gemmBlocks, 512, 0, stream>>>(hBuf, Bf3, xw40, asBuf, adBuf, 64, 1);
  aggregate40_lsm_kernel<<<nodeBlocks, 256, 0, stream>>>(xw40, asBuf, adBuf, rowPtr, colSrc, b3, out);
}